// Round 2
// baseline (1080.187 us; speedup 1.0000x reference)
//
#include <hip/hip_runtime.h>
#include <hip/hip_bf16.h>
#include <math.h>

// Problem constants
#define BATCH 4
#define SEQ   2048
#define DIM   1024
#define NH    16
#define DQK   64
#define DV    64
#define DIN   4
#define CHUNK 16
#define NC    128          // SEQ / CHUNK
#define KS    4
#define TOK   (BATCH*SEQ)  // 8192
#define SCALE 0.125f       // 1/sqrt(64)
#define BASE_LR 1e-3f
#define LN_EPS 1e-5f
#define K3    3072         // split-GEMM inner dim: [hi|hi|lo] x [hi|lo|hi]

typedef float f32x4 __attribute__((ext_vector_type(4)));
typedef short s16x8 __attribute__((ext_vector_type(8)));

// ---------------------------------------------------------------------------
// bf16 helpers (bit-level, no header-type dependence)
// ---------------------------------------------------------------------------
__device__ __forceinline__ unsigned short f2bf(float f) {
    unsigned u = __float_as_uint(f);
    u += 0x7fffu + ((u >> 16) & 1u);           // round-to-nearest-even
    return (unsigned short)(u >> 16);
}
__device__ __forceinline__ float bf2f(unsigned short h) {
    return __uint_as_float(((unsigned)h) << 16);
}

__device__ __forceinline__ void gload_lds16(const void* g, void* l) {
    __builtin_amdgcn_global_load_lds(
        (const __attribute__((address_space(1))) void*)g,
        (__attribute__((address_space(3))) void*)l, 16, 0, 0);
}

// ---------------------------------------------------------------------------
// Split f32 -> bf16 hi/lo, concatenated along K.
// wmode 0 (A side): cols [0,1024)=hi [1024,2048)=hi [2048,3072)=lo
// wmode 1 (B side): cols [0,1024)=hi [1024,2048)=lo [2048,3072)=hi
// ---------------------------------------------------------------------------
__global__ __launch_bounds__(256) void split_bf16_kernel(
    const float* __restrict__ X, unsigned short* __restrict__ Y,
    int rows, int wmode)
{
    const int idx = blockIdx.x * 256 + threadIdx.x;
    if (idx >= rows * (DIM / 4)) return;
    const int r  = idx >> 8;          // DIM/4 = 256 groups per row
    const int c4 = (idx & 255) << 2;

    float4 x = *(const float4*)(X + (size_t)r * DIM + c4);
    ushort4 hv, lv;
    hv.x = f2bf(x.x); lv.x = f2bf(x.x - bf2f(hv.x));
    hv.y = f2bf(x.y); lv.y = f2bf(x.y - bf2f(hv.y));
    hv.z = f2bf(x.z); lv.z = f2bf(x.z - bf2f(hv.z));
    hv.w = f2bf(x.w); lv.w = f2bf(x.w - bf2f(hv.w));

    const size_t rb = (size_t)r * K3;
    *(ushort4*)(Y + rb + c4)        = hv;
    *(ushort4*)(Y + rb + 1024 + c4) = wmode ? lv : hv;
    *(ushort4*)(Y + rb + 2048 + c4) = wmode ? hv : lv;
}

// ---------------------------------------------------------------------------
// MFMA GEMM (bf16, NT): C[M,N] = A'[M,K3] @ B'[N,K3]^T, f32 accumulate.
// 128x128 tile, BK=64, 4 waves (2x2, 64x64 each), mfma_f32_16x16x32_bf16.
// Staging: global_load_lds 16B with XOR chunk swizzle cs = c ^ (row&7)
// applied on the GLOBAL source (LDS dest linear, rule #21); ds_read_b128
// applies the same XOR -> 2 lanes/bank (conflict-free).
// M, N multiples of 128. LDS row stride = 64 bf16 = 128 B.
// ---------------------------------------------------------------------------
__global__ __launch_bounds__(256) void gemm_mfma_bt(
    const unsigned short* __restrict__ A, const unsigned short* __restrict__ B,
    float* __restrict__ C, int M, int N)
{
    __shared__ __align__(16) unsigned short sA[128 * 64];
    __shared__ __align__(16) unsigned short sB[128 * 64];

    const int tid  = threadIdx.x;
    const int lane = tid & 63;
    const int wav  = tid >> 6;
    const int m0 = blockIdx.y * 128;
    const int n0 = blockIdx.x * 128;
    const int wm = (wav >> 1) * 64;     // wave 2x2 -> 64x64 quadrant
    const int wn = (wav & 1) * 64;

    f32x4 acc[4][4] = {};

    const int fbase = wav * 64 + lane;
    const int lrow  = lane & 15;
    const int g     = lane >> 4;        // 0..3

    for (int kt = 0; kt < K3; kt += 64) {
        __syncthreads();                 // prior reads done before overwrite
#pragma unroll
        for (int i = 0; i < 4; ++i) {
            const int f  = fbase + i * 256;      // flat 16B slot 0..1023
            const int r  = f >> 3;               // tile row 0..127
            const int c  = (f & 7) ^ (r & 7);    // global chunk (pre-swizzled)
            const size_t go = (size_t)r * K3 + kt + c * 8;
            char* lb = (char*)sA + (wav * 64 + i * 256) * 16;  // wave-uniform
            gload_lds16(A + (size_t)m0 * K3 + go, lb);
        }
#pragma unroll
        for (int i = 0; i < 4; ++i) {
            const int f  = fbase + i * 256;
            const int r  = f >> 3;
            const int c  = (f & 7) ^ (r & 7);
            const size_t go = (size_t)r * K3 + kt + c * 8;
            char* lb = (char*)sB + (wav * 64 + i * 256) * 16;
            gload_lds16(B + (size_t)n0 * K3 + go, lb);
        }
        __syncthreads();                 // vmcnt(0) drained by compiler

#pragma unroll
        for (int ks = 0; ks < 2; ++ks) {
            const int cbase = ks * 4 + g;        // logical 8-elem chunk
            s16x8 af[4], bf[4];
#pragma unroll
            for (int mi = 0; mi < 4; ++mi) {
                const int r  = wm + mi * 16 + lrow;
                const int cs = cbase ^ (r & 7);
                af[mi] = *(const s16x8*)((const char*)sA + r * 128 + cs * 16);
            }
#pragma unroll
            for (int ni = 0; ni < 4; ++ni) {
                const int r  = wn + ni * 16 + lrow;
                const int cs = cbase ^ (r & 7);
                bf[ni] = *(const s16x8*)((const char*)sB + r * 128 + cs * 16);
            }
#pragma unroll
            for (int mi = 0; mi < 4; ++mi)
#pragma unroll
                for (int ni = 0; ni < 4; ++ni)
                    acc[mi][ni] = __builtin_amdgcn_mfma_f32_16x16x32_bf16(
                        af[mi], bf[ni], acc[mi][ni], 0, 0, 0);
        }
    }

    // epilogue: C/D layout col=lane&15, row=(lane>>4)*4+reg  [m89-verified]
    const int lcol = lane & 15;
    const int lq   = lane >> 4;
#pragma unroll
    for (int mi = 0; mi < 4; ++mi)
#pragma unroll
        for (int ni = 0; ni < 4; ++ni)
#pragma unroll
            for (int r = 0; r < 4; ++r) {
                const int m = m0 + wm + mi * 16 + lq * 4 + r;
                const int n = n0 + wn + ni * 16 + lcol;
                C[(size_t)m * N + n] = acc[mi][ni][r];
            }
}

// ---------------------------------------------------------------------------
// f32 GEMM (NT) — kept for the lr projection only (N=32).
// ---------------------------------------------------------------------------
#define GBM 128
#define GBN 128
#define GBK 8

__global__ __launch_bounds__(256) void gemm_nt_f32(
    const float* __restrict__ A, const float* __restrict__ B,
    float* __restrict__ C, int M, int N, int K)
{
    __shared__ float As[GBK][GBM + 4];
    __shared__ float Bs[GBK][GBN + 4];

    const int tid = threadIdx.x;
    const int m0 = blockIdx.y * GBM;
    const int n0 = blockIdx.x * GBN;
    const int la_m = tid >> 1;
    const int la_k = (tid & 1) << 2;
    const int tm = tid >> 4;
    const int tn = tid & 15;

    float acc[8][8] = {};

    const float* Arow = A + (size_t)(m0 + la_m) * K + la_k;
    const float* Brow = B + (size_t)(n0 + la_m) * K + la_k;
    const bool bvalid = (n0 + la_m) < N;

    for (int k0 = 0; k0 < K; k0 += GBK) {
        float4 av = *(const float4*)(Arow + k0);
        float4 bv = make_float4(0.f, 0.f, 0.f, 0.f);
        if (bvalid) bv = *(const float4*)(Brow + k0);

        __syncthreads();
        As[la_k + 0][la_m] = av.x; As[la_k + 1][la_m] = av.y;
        As[la_k + 2][la_m] = av.z; As[la_k + 3][la_m] = av.w;
        Bs[la_k + 0][la_m] = bv.x; Bs[la_k + 1][la_m] = bv.y;
        Bs[la_k + 2][la_m] = bv.z; Bs[la_k + 3][la_m] = bv.w;
        __syncthreads();

#pragma unroll
        for (int k = 0; k < GBK; ++k) {
            float4 a0 = *(const float4*)&As[k][tm * 8];
            float4 a1 = *(const float4*)&As[k][tm * 8 + 4];
            float4 b0 = *(const float4*)&Bs[k][tn * 8];
            float4 b1 = *(const float4*)&Bs[k][tn * 8 + 4];
            float a[8] = {a0.x, a0.y, a0.z, a0.w, a1.x, a1.y, a1.z, a1.w};
            float b[8] = {b0.x, b0.y, b0.z, b0.w, b1.x, b1.y, b1.z, b1.w};
#pragma unroll
            for (int i = 0; i < 8; ++i)
#pragma unroll
                for (int j = 0; j < 8; ++j)
                    acc[i][j] += a[i] * b[j];
        }
    }

#pragma unroll
    for (int i = 0; i < 8; ++i) {
        const int m = m0 + tm * 8 + i;
#pragma unroll
        for (int j = 0; j < 8; ++j) {
            const int n = n0 + tn * 8 + j;
            if (n < N) C[(size_t)m * N + n] = acc[i][j];
        }
    }
}

// ---------------------------------------------------------------------------
// Causal depthwise conv (KS=4) + identity residual.
// ---------------------------------------------------------------------------
__global__ __launch_bounds__(256) void conv_res_kernel(
    const float* __restrict__ x, const float* __restrict__ w,
    float* __restrict__ y)
{
    const int tid = blockIdx.x * blockDim.x + threadIdx.x;
    if (tid >= TOK * 256) return;
    const int c4  = (tid & 255) << 2;
    const int row = tid >> 8;
    const int t   = row & (SEQ - 1);

    const float* xp = x + (size_t)row * DIM + c4;
    float4 acc = *(const float4*)xp;      // residual
    float4 w0 = *(const float4*)(w + (c4 + 0) * 4);
    float4 w1 = *(const float4*)(w + (c4 + 1) * 4);
    float4 w2 = *(const float4*)(w + (c4 + 2) * 4);
    float4 w3 = *(const float4*)(w + (c4 + 3) * 4);

#pragma unroll
    for (int j = 0; j < 4; ++j) {
        const int tt = t - 3 + j;
        if (tt >= 0) {
            float4 xv = *(const float4*)(xp + (j - 3) * DIM);
            acc.x += xv.x * ((&w0.x)[j]);
            acc.y += xv.y * ((&w1.x)[j]);
            acc.z += xv.z * ((&w2.x)[j]);
            acc.w += xv.w * ((&w3.x)[j]);
        }
    }
    *(float4*)(y + (size_t)row * DIM + c4) = acc;
}

// ---------------------------------------------------------------------------
// lr chunk means: lrpre [B, SEQ, 32] -> lrm [B, NC, NH, 2]
// ---------------------------------------------------------------------------
__global__ __launch_bounds__(256) void lrmean_kernel(
    const float* __restrict__ lrpre, float* __restrict__ lrm)
{
    const int idx = blockIdx.x * blockDim.x + threadIdx.x;
    if (idx >= BATCH * NC * NH * 2) return;
    const int j = idx & 1;
    const int h = (idx >> 1) & 15;
    const int c = (idx >> 5) & 127;
    const int b = idx >> 12;

    float s = 0.f;
#pragma unroll
    for (int i = 0; i < CHUNK; ++i) {
        float x = lrpre[((size_t)b * SEQ + c * CHUNK + i) * 32 + h * 2 + j] + BASE_LR;
        s += fmaxf(x, 0.f) + log1pf(expf(-fabsf(x)));   // stable softplus
    }
    lrm[idx] = s * (1.f / CHUNK);
}

// ---------------------------------------------------------------------------
// Pass 1: sequential fast-weight state evolution (one wave per (b,h)).
// ---------------------------------------------------------------------------
__global__ __launch_bounds__(64) void state_scan_kernel(
    const float* __restrict__ kconv, const float* __restrict__ vconv,
    const float* __restrict__ lrm,
    const float* __restrict__ win_init, const float* __restrict__ wout_init,
    float* __restrict__ wst_in, float* __restrict__ wst_out)
{
    const int bh = blockIdx.x;
    const int b = bh >> 4, h = bh & 15;
    const int d = threadIdx.x;

    float win[DIN], wout[DIN];
#pragma unroll
    for (int n = 0; n < DIN; ++n) {
        win[n]  = win_init [(n * NH + h) * DQK + d];
        wout[n] = wout_init[(n * NH + h) * DV  + d];
    }

    __shared__ float sW[DIN][65];
    __shared__ float sK[CHUNK][65];
    __shared__ float sP1[DIN][CHUNK];
    __shared__ float sP2[DIN][CHUNK];

    const int gn = d >> 4;
    const int gc = d & 15;

    float kreg[CHUNK], vreg[CHUNK];

    for (int c = 0; c < NC; ++c) {
        const size_t wofs = (((size_t)bh * NC + c) * DIN) * 64 + d;
#pragma unroll
        for (int n = 0; n < DIN; ++n) {
            wst_in [wofs + n * 64] = win[n];
            wst_out[wofs + n * 64] = wout[n];
        }

        const size_t base = ((size_t)b * SEQ + c * CHUNK) * DIM + h * 64 + d;
#pragma unroll
        for (int i = 0; i < CHUNK; ++i) {
            kreg[i] = kconv[base + (size_t)i * DIM];
            vreg[i] = vconv[base + (size_t)i * DIM];
            sK[i][d] = kreg[i];
        }
#pragma unroll
        for (int n = 0; n < DIN; ++n) sW[n][d] = win[n];
        __syncthreads();

        float dot = 0.f;
#pragma unroll
        for (int dd = 0; dd < 64; ++dd) dot += sW[gn][dd] * sK[gc][dd];
        float g1 = dot * SCALE;
        float g2 = dot * (0.5f * SCALE);

        float m1 = g1, m2 = g2;
#pragma unroll
        for (int mk = 8; mk >= 1; mk >>= 1) {
            m1 = fmaxf(m1, __shfl_xor(m1, mk, 16));
            m2 = fmaxf(m2, __shfl_xor(m2, mk, 16));
        }
        float e1 = expf(g1 - m1), e2 = expf(g2 - m2);
        float s1 = e1, s2 = e2;
#pragma unroll
        for (int mk = 8; mk >= 1; mk >>= 1) {
            s1 += __shfl_xor(s1, mk, 16);
            s2 += __shfl_xor(s2, mk, 16);
        }
        sP1[gn][gc] = e1 / s1;
        sP2[gn][gc] = e2 / s2;
        __syncthreads();

        const float lr0 = lrm[(((size_t)b * NC + c) * NH + h) * 2 + 0];
        const float lr1 = lrm[(((size_t)b * NC + c) * NH + h) * 2 + 1];

#pragma unroll
        for (int n = 0; n < DIN; ++n) {
            float aI = 0.f, aO = 0.f;
#pragma unroll
            for (int ci = 0; ci < CHUNK; ++ci) {
                aI += sP2[n][ci] * kreg[ci];
                aO += sP1[n][ci] * vreg[ci];
            }
            win[n]  += lr0 * aI;
            wout[n] += lr1 * aO;
        }
        __syncthreads();
    }
}

// ---------------------------------------------------------------------------
// Pass 2: per-(b,h,chunk) attention + LayerNorm + gate. og aliases gate.
// ---------------------------------------------------------------------------
__global__ __launch_bounds__(64) void attn_kernel(
    const float* __restrict__ qconv, const float* __restrict__ kconv,
    const float* __restrict__ vconv,
    const float* __restrict__ wst_in, const float* __restrict__ wst_out,
    const float* __restrict__ gate,
    const float* __restrict__ gamma, const float* __restrict__ beta,
    float* __restrict__ og)
{
    const int blk = blockIdx.x;
    const int c  = blk & (NC - 1);
    const int bh = blk >> 7;
    const int h = bh & 15, b = bh >> 4;
    const int d = threadIdx.x;

    __shared__ float sQ[CHUNK][65];
    __shared__ float sKf[DIN + CHUNK][65];
    __shared__ float sS[CHUNK][21];
    __shared__ float sO[CHUNK][65];
    __shared__ float sMu[CHUNK], sRs[CHUNK];

    float vf[DIN + CHUNK];

    const size_t wofs = (size_t)blk * (DIN * 64) + d;
#pragma unroll
    for (int n = 0; n < DIN; ++n) {
        sKf[n][d] = wst_in [wofs + n * 64];
        vf[n]     = wst_out[wofs + n * 64];
    }
    const size_t base = ((size_t)b * SEQ + c * CHUNK) * DIM + h * 64 + d;
#pragma unroll
    for (int i = 0; i < CHUNK; ++i) {
        sQ[i][d]        = qconv[base + (size_t)i * DIM];
        sKf[DIN + i][d] = kconv[base + (size_t)i * DIM];
        vf[DIN + i]     = vconv[base + (size_t)i * DIM];
    }
    __syncthreads();

#pragma unroll
    for (int r = 0; r < 5; ++r) {
        const int p = d + 64 * r;
        const int t = p / 20, j = p % 20;
        float dot = 0.f;
#pragma unroll
        for (int dd = 0; dd < 64; ++dd) dot += sQ[t][dd] * sKf[j][dd];
        float s = dot * SCALE;
        if (j >= DIN && (j - DIN) > t) s = -3.0e38f;
        sS[t][j] = s;
    }
    __syncthreads();

    if (d < CHUNK) {
        float m = -3.0e38f;
#pragma unroll
        for (int j = 0; j < DIN + CHUNK; ++j) m = fmaxf(m, sS[d][j]);
        float e[DIN + CHUNK];
        float sum = 0.f;
#pragma unroll
        for (int j = 0; j < DIN + CHUNK; ++j) { e[j] = expf(sS[d][j] - m); sum += e[j]; }
        const float inv = 1.f / sum;
#pragma unroll
        for (int j = 0; j < DIN + CHUNK; ++j) sS[d][j] = e[j] * inv;
    }
    __syncthreads();

#pragma unroll
    for (int t = 0; t < CHUNK; ++t) {
        float o = 0.f;
#pragma unroll
        for (int j = 0; j < DIN + CHUNK; ++j) o += sS[t][j] * vf[j];
        sO[t][d] = o;
    }
    __syncthreads();

    if (d < CHUNK) {
        float su = 0.f, sq = 0.f;
#pragma unroll
        for (int dd = 0; dd < 64; ++dd) { float x = sO[d][dd]; su += x; sq += x * x; }
        float mu = su * (1.f / 64.f);
        float var = sq * (1.f / 64.f) - mu * mu;
        sMu[d] = mu;
        sRs[d] = rsqrtf(var + LN_EPS);
    }
    __syncthreads();

    const float gm = gamma[d], bt = beta[d];
#pragma unroll
    for (int t = 0; t < CHUNK; ++t) {
        float val = (sO[t][d] - sMu[t]) * sRs[t] * gm + bt;
        float gval = gate[base + (size_t)t * DIM];
        og[base + (size_t)t * DIM] = val * gval;
    }
}

// ---------------------------------------------------------------------------
extern "C" void kernel_launch(void* const* d_in, const int* in_sizes, int n_in,
                              void* d_out, int out_size, void* d_ws, size_t ws_size,
                              hipStream_t stream)
{
    const float* hid   = (const float*)d_in[0];
    const float* Wq    = (const float*)d_in[1];
    const float* Wk    = (const float*)d_in[2];
    const float* Wv    = (const float*)d_in[3];
    const float* Wlr   = (const float*)d_in[4];
    const float* Wo    = (const float*)d_in[5];
    const float* Wg    = (const float*)d_in[6];
    const float* cq    = (const float*)d_in[7];
    const float* ck    = (const float*)d_in[8];
    const float* cv    = (const float*)d_in[9];
    const float* wini  = (const float*)d_in[10];
    const float* wouti = (const float*)d_in[11];
    const float* lng   = (const float*)d_in[12];
    const float* lnb   = (const float*)d_in[13];
    float* out = (float*)d_out;

    float* ws = (float*)d_ws;
    const size_t DSZ = (size_t)TOK * DIM;
    float* lin   = ws;
    float* qv    = lin   + DSZ;
    float* kv    = qv    + DSZ;
    float* vv    = kv    + DSZ;
    float* gate  = vv    + DSZ;
    float* lrpre = gate  + DSZ;                        // TOK*32
    float* lrm   = lrpre + (size_t)TOK * 32;           // 16384
    float* wsti  = lrm   + BATCH * NC * NH * 2;
    float* wsto  = wsti  + (size_t)BATCH * NH * NC * DIN * 64;
    unsigned short* Abuf = (unsigned short*)(wsto + (size_t)BATCH * NH * NC * DIN * 64);
    unsigned short* Bbuf = Abuf + (size_t)TOK * K3;    // [1024][K3]

    const int M = TOK, K = DIM;
    const dim3 blk256(256);
    const dim3 mfma_grid(DIM / 128, M / 128);          // (8, 64)
    const dim3 gemm_grid_lr(1, M / GBM);
    const int conv_blocks = (TOK * 256 + 255) / 256;
    const int splitA_blocks = TOK;                     // TOK*256/256
    const int splitW_blocks = 1024;                    // 1024*256/256

    // hidden split (used by q/k/v/gate GEMMs)
    split_bf16_kernel<<<splitA_blocks, blk256, 0, stream>>>(hid, Abuf, TOK, 0);

    // q
    split_bf16_kernel<<<splitW_blocks, blk256, 0, stream>>>(Wq, Bbuf, DIM, 1);
    gemm_mfma_bt<<<mfma_grid, blk256, 0, stream>>>(Abuf, Bbuf, lin, M, DIM);
    conv_res_kernel<<<conv_blocks, blk256, 0, stream>>>(lin, cq, qv);
    // k
    split_bf16_kernel<<<splitW_blocks, blk256, 0, stream>>>(Wk, Bbuf, DIM, 1);
    gemm_mfma_bt<<<mfma_grid, blk256, 0, stream>>>(Abuf, Bbuf, lin, M, DIM);
    conv_res_kernel<<<conv_blocks, blk256, 0, stream>>>(lin, ck, kv);
    // v
    split_bf16_kernel<<<splitW_blocks, blk256, 0, stream>>>(Wv, Bbuf, DIM, 1);
    gemm_mfma_bt<<<mfma_grid, blk256, 0, stream>>>(Abuf, Bbuf, lin, M, DIM);
    conv_res_kernel<<<conv_blocks, blk256, 0, stream>>>(lin, cv, vv);
    // lr (f32 path, N=32)
    gemm_nt_f32<<<gemm_grid_lr, blk256, 0, stream>>>(hid, Wlr, lrpre, M, 32, K);
    lrmean_kernel<<<(BATCH * NC * NH * 2 + 255) / 256, blk256, 0, stream>>>(lrpre, lrm);
    // gate
    split_bf16_kernel<<<splitW_blocks, blk256, 0, stream>>>(Wg, Bbuf, DIM, 1);
    gemm_mfma_bt<<<mfma_grid, blk256, 0, stream>>>(Abuf, Bbuf, gate, M, DIM);

    // fast-weight state scan + attention
    state_scan_kernel<<<BATCH * NH, 64, 0, stream>>>(kv, vv, lrm, wini, wouti, wsti, wsto);
    attn_kernel<<<BATCH * NH * NC, 64, 0, stream>>>(qv, kv, vv, wsti, wsto,
                                                    gate, lng, lnb, gate);

    // output projection: (o*gate) @ Wo^T   (Abuf no longer needed -> reuse)
    split_bf16_kernel<<<splitA_blocks, blk256, 0, stream>>>(gate, Abuf, TOK, 0);
    split_bf16_kernel<<<splitW_blocks, blk256, 0, stream>>>(Wo, Bbuf, DIM, 1);
    gemm_mfma_bt<<<mfma_grid, blk256, 0, stream>>>(Abuf, Bbuf, out, M, DIM);
}

// Round 6
// 982.481 us; speedup vs baseline: 1.0994x; 1.0994x over previous
//
#include <hip/hip_runtime.h>
#include <hip/hip_bf16.h>
#include <math.h>

// Problem constants
#define BATCH 4
#define SEQ   2048
#define DIM   1024
#define NH    16
#define DQK   64
#define DV    64
#define DIN   4
#define CHUNK 16
#define NC    128          // SEQ / CHUNK
#define KS    4
#define TOK   (BATCH*SEQ)  // 8192
#define SCALE 0.125f       // 1/sqrt(64)
#define BASE_LR 1e-3f
#define LN_EPS 1e-5f
#define K3    3072         // split-GEMM inner dim: [hi|hi|lo] x [hi|lo|hi]

typedef float f32x4 __attribute__((ext_vector_type(4)));
typedef short s16x8 __attribute__((ext_vector_type(8)));

// ---------------------------------------------------------------------------
// bf16 helpers (bit-level, no header-type dependence)
// ---------------------------------------------------------------------------
__device__ __forceinline__ unsigned short f2bf(float f) {
    unsigned u = __float_as_uint(f);
    u += 0x7fffu + ((u >> 16) & 1u);           // round-to-nearest-even
    return (unsigned short)(u >> 16);
}
__device__ __forceinline__ float bf2f(unsigned short h) {
    return __uint_as_float(((unsigned)h) << 16);
}

__device__ __forceinline__ void gload_lds16(const void* g, void* l) {
    __builtin_amdgcn_global_load_lds(
        (const __attribute__((address_space(1))) void*)g,
        (__attribute__((address_space(3))) void*)l, 16, 0, 0);
}

// ---------------------------------------------------------------------------
// Split f32 -> bf16 hi/lo, concatenated along K.
// wmode 0 (A side): cols [0,1024)=hi [1024,2048)=hi [2048,3072)=lo
// wmode 1 (B side): cols [0,1024)=hi [1024,2048)=lo [2048,3072)=hi
// ---------------------------------------------------------------------------
__global__ __launch_bounds__(256) void split_bf16_kernel(
    const float* __restrict__ X, unsigned short* __restrict__ Y,
    int rows, int wmode)
{
    const int idx = blockIdx.x * 256 + threadIdx.x;
    if (idx >= rows * (DIM / 4)) return;
    const int r  = idx >> 8;          // DIM/4 = 256 groups per row
    const int c4 = (idx & 255) << 2;

    float4 x = *(const float4*)(X + (size_t)r * DIM + c4);
    ushort4 hv, lv;
    hv.x = f2bf(x.x); lv.x = f2bf(x.x - bf2f(hv.x));
    hv.y = f2bf(x.y); lv.y = f2bf(x.y - bf2f(hv.y));
    hv.z = f2bf(x.z); lv.z = f2bf(x.z - bf2f(hv.z));
    hv.w = f2bf(x.w); lv.w = f2bf(x.w - bf2f(hv.w));

    const size_t rb = (size_t)r * K3;
    *(ushort4*)(Y + rb + c4)        = hv;
    *(ushort4*)(Y + rb + 1024 + c4) = wmode ? lv : hv;
    *(ushort4*)(Y + rb + 2048 + c4) = wmode ? hv : lv;
}

// ---------------------------------------------------------------------------
// Fused MFMA GEMM (bf16, NT): [q|k|v|gate] = A'[8192,K3] @ B'[4096,K3]^T.
// N fixed 4096 (grid x=32), M=8192 (grid y=64) -> 2048 wgs.
// Output scatter: tiles are 128-wide and 1024-aligned, so the target buffer
// (q/k/v/g) is WAVE-UNIFORM per tile (no per-lane pointer indexing).
// ---------------------------------------------------------------------------
__global__ __launch_bounds__(256) void gemm_mfma_qkvg(
    const unsigned short* __restrict__ A, const unsigned short* __restrict__ B,
    float* __restrict__ Cq, float* __restrict__ Ck,
    float* __restrict__ Cv, float* __restrict__ Cg)
{
    __shared__ __align__(16) unsigned short sA[128 * 64];
    __shared__ __align__(16) unsigned short sB[128 * 64];

    const int tid  = threadIdx.x;
    const int lane = tid & 63;
    const int wav  = tid >> 6;

    // XCD-aware swizzle (nwg = 2048, multiple of 8 -> bijective)
    const int nbx = gridDim.x;                  // 32
    const int nwg = nbx * gridDim.y;            // 2048
    int flat = blockIdx.x + blockIdx.y * nbx;
    const int per = nwg >> 3;
    flat = (flat & 7) * per + (flat >> 3);
    const int m0 = (flat / nbx) * 128;
    const int n0 = (flat % nbx) * 128;          // 0..3968

    const int wm = (wav >> 1) * 64;
    const int wn = (wav & 1) * 64;

    f32x4 acc[4][4] = {};

    const int fbase = wav * 64 + lane;
    const int lrow  = lane & 15;
    const int g     = lane >> 4;

    for (int kt = 0; kt < K3; kt += 64) {
        __syncthreads();
#pragma unroll
        for (int i = 0; i < 4; ++i) {
            const int f  = fbase + i * 256;
            const int r  = f >> 3;
            const int c  = (f & 7) ^ (r & 7);
            const size_t go = (size_t)r * K3 + kt + c * 8;
            char* lb = (char*)sA + (wav * 64 + i * 256) * 16;
            gload_lds16(A + (size_t)m0 * K3 + go, lb);
        }
#pragma unroll
        for (int i = 0; i < 4; ++i) {
            const int f  = fbase + i * 256;
            const int r  = f >> 3;
            const int c  = (f & 7) ^ (r & 7);
            const size_t go = (size_t)r * K3 + kt + c * 8;
            char* lb = (char*)sB + (wav * 64 + i * 256) * 16;
            gload_lds16(B + (size_t)n0 * K3 + go, lb);
        }
        __syncthreads();

#pragma unroll
        for (int ks = 0; ks < 2; ++ks) {
            const int cbase = ks * 4 + g;
            s16x8 af[4], bfr[4];
#pragma unroll
            for (int mi = 0; mi < 4; ++mi) {
                const int r  = wm + mi * 16 + lrow;
                const int cs = cbase ^ (r & 7);
                af[mi] = *(const s16x8*)((const char*)sA + r * 128 + cs * 16);
            }
#pragma unroll
            for (int ni = 0; ni < 4; ++ni) {
                const int r  = wn + ni * 16 + lrow;
                const int cs = cbase ^ (r & 7);
                bfr[ni] = *(const s16x8*)((const char*)sB + r * 128 + cs * 16);
            }
#pragma unroll
            for (int mi = 0; mi < 4; ++mi)
#pragma unroll
                for (int ni = 0; ni < 4; ++ni)
                    acc[mi][ni] = __builtin_amdgcn_mfma_f32_16x16x32_bf16(
                        af[mi], bfr[ni], acc[mi][ni], 0, 0, 0);
        }
    }

    // epilogue: wave-uniform output-buffer select (tile never straddles 1024)
    const int nblk = n0 >> 10;
    float* __restrict__ Co = (nblk == 0) ? Cq : (nblk == 1) ? Ck
                           : (nblk == 2) ? Cv : Cg;
    const int nc0 = (n0 & 1023) + wn;
    const int lcol = lane & 15;
    const int lq   = lane >> 4;
#pragma unroll
    for (int mi = 0; mi < 4; ++mi)
#pragma unroll
        for (int ni = 0; ni < 4; ++ni)
#pragma unroll
            for (int r = 0; r < 4; ++r) {
                const int m = m0 + wm + mi * 16 + lq * 4 + r;
                const int n = nc0 + ni * 16 + lcol;
                Co[(size_t)m * DIM + n] = acc[mi][ni][r];
            }
}

// ---------------------------------------------------------------------------
// MFMA GEMM (bf16, NT), single output: used for the final Wo projection.
// ---------------------------------------------------------------------------
__global__ __launch_bounds__(256) void gemm_mfma_bt(
    const unsigned short* __restrict__ A, const unsigned short* __restrict__ B,
    float* __restrict__ C, int M, int N)
{
    __shared__ __align__(16) unsigned short sA[128 * 64];
    __shared__ __align__(16) unsigned short sB[128 * 64];

    const int tid  = threadIdx.x;
    const int lane = tid & 63;
    const int wav  = tid >> 6;

    const int nbx = gridDim.x;
    const int nwg = nbx * gridDim.y;
    int flat = blockIdx.x + blockIdx.y * nbx;
    const int per = nwg >> 3;
    flat = (flat & 7) * per + (flat >> 3);
    const int m0 = (flat / nbx) * 128;
    const int n0 = (flat % nbx) * 128;

    const int wm = (wav >> 1) * 64;
    const int wn = (wav & 1) * 64;

    f32x4 acc[4][4] = {};

    const int fbase = wav * 64 + lane;
    const int lrow  = lane & 15;
    const int g     = lane >> 4;

    for (int kt = 0; kt < K3; kt += 64) {
        __syncthreads();
#pragma unroll
        for (int i = 0; i < 4; ++i) {
            const int f  = fbase + i * 256;
            const int r  = f >> 3;
            const int c  = (f & 7) ^ (r & 7);
            const size_t go = (size_t)r * K3 + kt + c * 8;
            char* lb = (char*)sA + (wav * 64 + i * 256) * 16;
            gload_lds16(A + (size_t)m0 * K3 + go, lb);
        }
#pragma unroll
        for (int i = 0; i < 4; ++i) {
            const int f  = fbase + i * 256;
            const int r  = f >> 3;
            const int c  = (f & 7) ^ (r & 7);
            const size_t go = (size_t)r * K3 + kt + c * 8;
            char* lb = (char*)sB + (wav * 64 + i * 256) * 16;
            gload_lds16(B + (size_t)n0 * K3 + go, lb);
        }
        __syncthreads();

#pragma unroll
        for (int ks = 0; ks < 2; ++ks) {
            const int cbase = ks * 4 + g;
            s16x8 af[4], bfr[4];
#pragma unroll
            for (int mi = 0; mi < 4; ++mi) {
                const int r  = wm + mi * 16 + lrow;
                const int cs = cbase ^ (r & 7);
                af[mi] = *(const s16x8*)((const char*)sA + r * 128 + cs * 16);
            }
#pragma unroll
            for (int ni = 0; ni < 4; ++ni) {
                const int r  = wn + ni * 16 + lrow;
                const int cs = cbase ^ (r & 7);
                bfr[ni] = *(const s16x8*)((const char*)sB + r * 128 + cs * 16);
            }
#pragma unroll
            for (int mi = 0; mi < 4; ++mi)
#pragma unroll
                for (int ni = 0; ni < 4; ++ni)
                    acc[mi][ni] = __builtin_amdgcn_mfma_f32_16x16x32_bf16(
                        af[mi], bfr[ni], acc[mi][ni], 0, 0, 0);
        }
    }

    const int lcol = lane & 15;
    const int lq   = lane >> 4;
#pragma unroll
    for (int mi = 0; mi < 4; ++mi)
#pragma unroll
        for (int ni = 0; ni < 4; ++ni)
#pragma unroll
            for (int r = 0; r < 4; ++r) {
                const int m = m0 + wm + mi * 16 + lq * 4 + r;
                const int n = n0 + wn + ni * 16 + lcol;
                C[(size_t)m * N + n] = acc[mi][ni][r];
            }
}

// ---------------------------------------------------------------------------
// f32 GEMM (NT) — kept for the lr projection only (N=32).
// ---------------------------------------------------------------------------
#define GBM 128
#define GBN 128
#define GBK 8

__global__ __launch_bounds__(256) void gemm_nt_f32(
    const float* __restrict__ A, const float* __restrict__ B,
    float* __restrict__ C, int M, int N, int K)
{
    __shared__ float As[GBK][GBM + 4];
    __shared__ float Bs[GBK][GBN + 4];

    const int tid = threadIdx.x;
    const int m0 = blockIdx.y * GBM;
    const int n0 = blockIdx.x * GBN;
    const int la_m = tid >> 1;
    const int la_k = (tid & 1) << 2;
    const int tm = tid >> 4;
    const int tn = tid & 15;

    float acc[8][8] = {};

    const float* Arow = A + (size_t)(m0 + la_m) * K + la_k;
    const float* Brow = B + (size_t)(n0 + la_m) * K + la_k;
    const bool bvalid = (n0 + la_m) < N;

    for (int k0 = 0; k0 < K; k0 += GBK) {
        float4 av = *(const float4*)(Arow + k0);
        float4 bv = make_float4(0.f, 0.f, 0.f, 0.f);
        if (bvalid) bv = *(const float4*)(Brow + k0);

        __syncthreads();
        As[la_k + 0][la_m] = av.x; As[la_k + 1][la_m] = av.y;
        As[la_k + 2][la_m] = av.z; As[la_k + 3][la_m] = av.w;
        Bs[la_k + 0][la_m] = bv.x; Bs[la_k + 1][la_m] = bv.y;
        Bs[la_k + 2][la_m] = bv.z; Bs[la_k + 3][la_m] = bv.w;
        __syncthreads();

#pragma unroll
        for (int k = 0; k < GBK; ++k) {
            float4 a0 = *(const float4*)&As[k][tm * 8];
            float4 a1 = *(const float4*)&As[k][tm * 8 + 4];
            float4 b0 = *(const float4*)&Bs[k][tn * 8];
            float4 b1 = *(const float4*)&Bs[k][tn * 8 + 4];
            float a[8] = {a0.x, a0.y, a0.z, a0.w, a1.x, a1.y, a1.z, a1.w};
            float b[8] = {b0.x, b0.y, b0.z, b0.w, b1.x, b1.y, b1.z, b1.w};
#pragma unroll
            for (int i = 0; i < 8; ++i)
#pragma unroll
                for (int j = 0; j < 8; ++j)
                    acc[i][j] += a[i] * b[j];
        }
    }

#pragma unroll
    for (int i = 0; i < 8; ++i) {
        const int m = m0 + tm * 8 + i;
#pragma unroll
        for (int j = 0; j < 8; ++j) {
            const int n = n0 + tn * 8 + j;
            if (n < N) C[(size_t)m * N + n] = acc[i][j];
        }
    }
}

// ---------------------------------------------------------------------------
// Causal depthwise conv (KS=4) + identity residual.
// ---------------------------------------------------------------------------
__global__ __launch_bounds__(256) void conv_res_kernel(
    const float* __restrict__ x, const float* __restrict__ w,
    float* __restrict__ y)
{
    const int tid = blockIdx.x * blockDim.x + threadIdx.x;
    if (tid >= TOK * 256) return;
    const int c4  = (tid & 255) << 2;
    const int row = tid >> 8;
    const int t   = row & (SEQ - 1);

    const float* xp = x + (size_t)row * DIM + c4;
    float4 acc = *(const float4*)xp;      // residual
    float4 w0 = *(const float4*)(w + (c4 + 0) * 4);
    float4 w1 = *(const float4*)(w + (c4 + 1) * 4);
    float4 w2 = *(const float4*)(w + (c4 + 2) * 4);
    float4 w3 = *(const float4*)(w + (c4 + 3) * 4);

#pragma unroll
    for (int j = 0; j < 4; ++j) {
        const int tt = t - 3 + j;
        if (tt >= 0) {
            float4 xv = *(const float4*)(xp + (j - 3) * DIM);
            acc.x += xv.x * ((&w0.x)[j]);
            acc.y += xv.y * ((&w1.x)[j]);
            acc.z += xv.z * ((&w2.x)[j]);
            acc.w += xv.w * ((&w3.x)[j]);
        }
    }
    *(float4*)(y + (size_t)row * DIM + c4) = acc;
}

// ---------------------------------------------------------------------------
// lr chunk means: lrpre [B, SEQ, 32] -> lrm [B, NC, NH, 2]
// ---------------------------------------------------------------------------
__global__ __launch_bounds__(256) void lrmean_kernel(
    const float* __restrict__ lrpre, float* __restrict__ lrm)
{
    const int idx = blockIdx.x * blockDim.x + threadIdx.x;
    if (idx >= BATCH * NC * NH * 2) return;
    const int j = idx & 1;
    const int h = (idx >> 1) & 15;
    const int c = (idx >> 5) & 127;
    const int b = idx >> 12;

    float s = 0.f;
#pragma unroll
    for (int i = 0; i < CHUNK; ++i) {
        float x = lrpre[((size_t)b * SEQ + c * CHUNK + i) * 32 + h * 2 + j] + BASE_LR;
        s += fmaxf(x, 0.f) + log1pf(expf(-fabsf(x)));   // stable softplus
    }
    lrm[idx] = s * (1.f / CHUNK);
}

// ---------------------------------------------------------------------------
// Pass 1: sequential fast-weight state evolution (one wave per (b,h)).
// Register double-buffer prefetch of k/v; raw s_waitcnt lgkmcnt(0) instead of
// __syncthreads (block = 1 wave -> barrier no-op; avoids the compiler's
// vmcnt(0) drain that would serialize the prefetch); float4 LDS reads; lr
// preloaded to LDS. Accumulation order identical to round-2 (bit-exact).
// ---------------------------------------------------------------------------
__global__ __launch_bounds__(64) void state_scan_kernel(
    const float* __restrict__ kconv, const float* __restrict__ vconv,
    const float* __restrict__ lrm,
    const float* __restrict__ win_init, const float* __restrict__ wout_init,
    float* __restrict__ wst_in, float* __restrict__ wst_out)
{
    const int bh = blockIdx.x;
    const int b = bh >> 4, h = bh & 15;
    const int d = threadIdx.x;          // 0..63

    __shared__ __align__(16) float sW[DIN][68];
    __shared__ __align__(16) float sK[CHUNK][68];
    __shared__ __align__(16) float sP1[DIN][16];
    __shared__ __align__(16) float sP2[DIN][16];
    __shared__ float sLR[NC * 2];

    float win[DIN], wout[DIN];
#pragma unroll
    for (int n = 0; n < DIN; ++n) {
        win[n]  = win_init [(n * NH + h) * DQK + d];
        wout[n] = wout_init[(n * NH + h) * DV  + d];
    }
#pragma unroll
    for (int i = 0; i < 4; ++i) {
        const int idx = d * 4 + i;
        const int c = idx >> 1, j = idx & 1;
        sLR[idx] = lrm[(((size_t)b * NC + c) * NH + h) * 2 + j];
    }

    const int gn = d >> 4;
    const int gc = d & 15;

    float ka[CHUNK], va[CHUNK], kb[CHUNK], vb[CHUNK];

    const size_t base00 = (size_t)b * SEQ * DIM + h * 64 + d;
#pragma unroll
    for (int i = 0; i < CHUNK; ++i) {
        ka[i] = kconv[base00 + (size_t)i * DIM];
        va[i] = vconv[base00 + (size_t)i * DIM];
    }
    asm volatile("s_waitcnt lgkmcnt(0)" ::: "memory");   // sLR visible

#define SCAN_STEP(c, KC, VC, KN, VN)                                           \
    {                                                                          \
        if ((c) + 1 < NC) {                                                    \
            const size_t basen = base00 + (size_t)(((c) + 1) * CHUNK) * DIM;   \
            _Pragma("unroll")                                                  \
            for (int i = 0; i < CHUNK; ++i) {                                  \
                KN[i] = kconv[basen + (size_t)i * DIM];                        \
                VN[i] = vconv[basen + (size_t)i * DIM];                        \
            }                                                                  \
        }                                                                      \
        const size_t wofs = (((size_t)bh * NC + (c)) * DIN) * 64 + d;          \
        _Pragma("unroll")                                                      \
        for (int n = 0; n < DIN; ++n) {                                        \
            wst_in [wofs + n * 64] = win[n];                                   \
            wst_out[wofs + n * 64] = wout[n];                                  \
        }                                                                      \
        _Pragma("unroll")                                                      \
        for (int i = 0; i < CHUNK; ++i) sK[i][d] = KC[i];                      \
        _Pragma("unroll")                                                      \
        for (int n = 0; n < DIN; ++n) sW[n][d] = win[n];                       \
        asm volatile("s_waitcnt lgkmcnt(0)" ::: "memory");                     \
        float dot = 0.f;                                                       \
        _Pragma("unroll")                                                      \
        for (int q = 0; q < 16; ++q) {                                         \
            float4 wv = *(const float4*)&sW[gn][q * 4];                        \
            float4 xv = *(const float4*)&sK[gc][q * 4];                        \
            dot += wv.x * xv.x; dot += wv.y * xv.y;                            \
            dot += wv.z * xv.z; dot += wv.w * xv.w;                            \
        }                                                                      \
        float g1 = dot * SCALE;                                                \
        float g2 = dot * (0.5f * SCALE);                                       \
        float m1 = g1, m2 = g2;                                                \
        _Pragma("unroll")                                                      \
        for (int mk = 8; mk >= 1; mk >>= 1) {                                  \
            m1 = fmaxf(m1, __shfl_xor(m1, mk, 16));                            \
            m2 = fmaxf(m2, __shfl_xor(m2, mk, 16));                            \
        }                                                                      \
        float e1 = expf(g1 - m1), e2 = expf(g2 - m2);                          \
        float s1 = e1, s2 = e2;                                                \
        _Pragma("unroll")                                                      \
        for (int mk = 8; mk >= 1; mk >>= 1) {                                  \
            s1 += __shfl_xor(s1, mk, 16);                                      \
            s2 += __shfl_xor(s2, mk, 16);                                      \
        }                                                                      \
        sP1[gn][gc] = e1 / s1;                                                 \
        sP2[gn][gc] = e2 / s2;                                                 \
        asm volatile("s_waitcnt lgkmcnt(0)" ::: "memory");                     \
        const float lr0 = sLR[(c) * 2 + 0];                                    \
        const float lr1 = sLR[(c) * 2 + 1];                                    \
        _Pragma("unroll")                                                      \
        for (int n = 0; n < DIN; ++n) {                                        \
            float aI = 0.f, aO = 0.f;                                          \
            _Pragma("unroll")                                                  \
            for (int q = 0; q < 4; ++q) {                                      \
                float4 p2 = *(const float4*)&sP2[n][q * 4];                    \
                float4 p1 = *(const float4*)&sP1[n][q * 4];                    \
                aI += p2.x * KC[q * 4 + 0]; aI += p2.y * KC[q * 4 + 1];        \
                aI += p2.z * KC[q * 4 + 2]; aI += p2.w * KC[q * 4 + 3];        \
                aO += p1.x * VC[q * 4 + 0]; aO += p1.y * VC[q * 4 + 1];        \
                aO += p1.z * VC[q * 4 + 2]; aO += p1.w * VC[q * 4 + 3];        \
            }                                                                  \
            win[n]  += lr0 * aI;                                               \
            wout[n] += lr1 * aO;                                               \
        }                                                                      \
        asm volatile("s_waitcnt lgkmcnt(0)" ::: "memory");                     \
    }

    for (int c = 0; c < NC; c += 2) {
        SCAN_STEP(c,     ka, va, kb, vb);
        SCAN_STEP(c + 1, kb, vb, ka, va);
    }
#undef SCAN_STEP
}

// ---------------------------------------------------------------------------
// Pass 2: per-(b,h,chunk) attention + LayerNorm + gate.
// og may alias qconv: each block loads its full q-slice into LDS before
// writing the identical og slice (block-local, race-free).
// ---------------------------------------------------------------------------
__global__ __launch_bounds__(64) void attn_kernel(
    const float* __restrict__ qconv, const float* __restrict__ kconv,
    const float* __restrict__ vconv,
    const float* __restrict__ wst_in, const float* __restrict__ wst_out,
    const float* __restrict__ gate,
    const float* __restrict__ gamma, const float* __restrict__ beta,
    float* __restrict__ og)
{
    const int blk = blockIdx.x;
    const int c  = blk & (NC - 1);
    const int bh = blk >> 7;
    const int h = bh & 15, b = bh >> 4;
    const int d = threadIdx.x;

    __shared__ float sQ[CHUNK][65];
    __shared__ float sKf[DIN + CHUNK][65];
    __shared__ float sS[CHUNK][21];
    __shared__ float sO[CHUNK][65];
    __shared__ float sMu[CHUNK], sRs[CHUNK];

    float vf[DIN + CHUNK];

    const size_t wofs = (size_t)blk * (DIN * 64) + d;
#pragma unroll
    for (int n = 0; n < DIN; ++n) {
        sKf[n][d] = wst_in [wofs + n * 64];
        vf[n]     = wst_out[wofs + n * 64];
    }
    const size_t base = ((size_t)b * SEQ + c * CHUNK) * DIM + h * 64 + d;
#pragma unroll
    for (int i = 0; i < CHUNK; ++i) {
        sQ[i][d]        = qconv[base + (size_t)i * DIM];
        sKf[DIN + i][d] = kconv[base + (size_t)i * DIM];
        vf[DIN + i]     = vconv[base + (size_t)i * DIM];
    }
    __syncthreads();

#pragma unroll
    for (int r = 0; r < 5; ++r) {
        const int p = d + 64 * r;
        const int t = p / 20, j = p % 20;
        float dot = 0.f;
#pragma unroll
        for (int dd = 0; dd < 64; ++dd) dot += sQ[t][dd] * sKf[j][dd];
        float s = dot * SCALE;
        if (j >= DIN && (j - DIN) > t) s = -3.0e38f;
        sS[t][j] = s;
    }
    __syncthreads();

    if (d < CHUNK) {
        float m = -3.0e38f;
#pragma unroll
        for (int j = 0; j < DIN + CHUNK; ++j) m = fmaxf(m, sS[d][j]);
        float e[DIN + CHUNK];
        float sum = 0.f;
#pragma unroll
        for (int j = 0; j < DIN + CHUNK; ++j) { e[j] = expf(sS[d][j] - m); sum += e[j]; }
        const float inv = 1.f / sum;
#pragma unroll
        for (int j = 0; j < DIN + CHUNK; ++j) sS[d][j] = e[j] * inv;
    }
    __syncthreads();

#pragma unroll
    for (int t = 0; t < CHUNK; ++t) {
        float o = 0.f;
#pragma unroll
        for (int j = 0; j < DIN + CHUNK; ++j) o += sS[t][j] * vf[j];
        sO[t][d] = o;
    }
    __syncthreads();

    if (d < CHUNK) {
        float su = 0.f, sq = 0.f;
#pragma unroll
        for (int dd = 0; dd < 64; ++dd) { float x = sO[d][dd]; su += x; sq += x * x; }
        float mu = su * (1.f / 64.f);
        float var = sq * (1.f / 64.f) - mu * mu;
        sMu[d] = mu;
        sRs[d] = rsqrtf(var + LN_EPS);
    }
    __syncthreads();

    const float gm = gamma[d], bt = beta[d];
#pragma unroll
    for (int t = 0; t < CHUNK; ++t) {
        float val = (sO[t][d] - sMu[t]) * sRs[t] * gm + bt;
        float gval = gate[base + (size_t)t * DIM];
        og[base + (size_t)t * DIM] = val * gval;
    }
}

// ---------------------------------------------------------------------------
// Workspace layout (high-water ~236.4 MB; round-2's 242.2 MB layout passed):
//   qraw kraw vraw gatb (4x 33.55 MB f32)
//   lrpre (1 MB)  lrm  wsti wsto (16.8 MB)
//   Abuf (50.3 MB bf16)
//   Bbuf (25.2 MB bf16)  <-- ALIASED by spar (33.55 MB f32, extends past Bbuf
//                            but within the proven ws bound)
// spar/Bbuf lifetime disjointness (all dispatches serialized on one stream):
//   Bbuf live: weight-splits -> fused GEMM;  Wo-split -> final GEMM.
//   spar live: conv-q -> attn -> split(qv->Abuf). The Wo-split overwrites
//   spar only AFTER split(qv->Abuf) consumed it.
// ---------------------------------------------------------------------------
extern "C" void kernel_launch(void* const* d_in, const int* in_sizes, int n_in,
                              void* d_out, int out_size, void* d_ws, size_t ws_size,
                              hipStream_t stream)
{
    const float* hid   = (const float*)d_in[0];
    const float* Wq    = (const float*)d_in[1];
    const float* Wk    = (const float*)d_in[2];
    const float* Wv    = (const float*)d_in[3];
    const float* Wlr   = (const float*)d_in[4];
    const float* Wo    = (const float*)d_in[5];
    const float* Wg    = (const float*)d_in[6];
    const float* cq    = (const float*)d_in[7];
    const float* ck    = (const float*)d_in[8];
    const float* cv    = (const float*)d_in[9];
    const float* wini  = (const float*)d_in[10];
    const float* wouti = (const float*)d_in[11];
    const float* lng   = (const float*)d_in[12];
    const float* lnb   = (const float*)d_in[13];
    float* out = (float*)d_out;

    float* ws = (float*)d_ws;
    const size_t DSZ = (size_t)TOK * DIM;
    float* qraw  = ws;
    float* kraw  = qraw + DSZ;
    float* vraw  = kraw + DSZ;
    float* gatb  = vraw + DSZ;
    float* lrpre = gatb + DSZ;                         // TOK*32
    float* lrm   = lrpre + (size_t)TOK * 32;           // 16384
    float* wsti  = lrm   + BATCH * NC * NH * 2;
    float* wsto  = wsti  + (size_t)BATCH * NH * NC * DIN * 64;
    unsigned short* Abuf = (unsigned short*)(wsto + (size_t)BATCH * NH * NC * DIN * 64);
    unsigned short* Bbuf = Abuf + (size_t)TOK * K3;    // [4096][K3]
    float* spar = (float*)Bbuf;        // aliases Bbuf (disjoint lifetimes)

    // buffer ping-pong: qv = spar, kv = qraw, vv = kraw (after convs)
    float* qv = spar;
    float* kv = qraw;
    float* vv = kraw;

    const dim3 blk256(256);
    const dim3 fused_grid(32, 64);                     // N=4096 tiles x M tiles
    const dim3 out_grid(8, 64);                        // final Wo GEMM
    const dim3 gemm_grid_lr(1, TOK / GBM);
    const int conv_blocks = (TOK * 256 + 255) / 256;

    // splits: hidden -> Abuf; 4 weights -> Bbuf row blocks
    split_bf16_kernel<<<TOK, blk256, 0, stream>>>(hid, Abuf, TOK, 0);
    split_bf16_kernel<<<1024, blk256, 0, stream>>>(Wq, Bbuf,                       1024, 1);
    split_bf16_kernel<<<1024, blk256, 0, stream>>>(Wk, Bbuf + (size_t)1024 * K3,   1024, 1);
    split_bf16_kernel<<<1024, blk256, 0, stream>>>(Wv, Bbuf + (size_t)2048 * K3,   1024, 1);
    split_bf16_kernel<<<1024, blk256, 0, stream>>>(Wg, Bbuf + (size_t)3072 * K3,   1024, 1);

    // fused q/k/v/gate projection
    gemm_mfma_qkvg<<<fused_grid, blk256, 0, stream>>>(Abuf, Bbuf, qraw, kraw, vraw, gatb);

    // convs (ordering matters: each reads the buffer the next one overwrites;
    // conv-q's write to spar retires Bbuf)
    conv_res_kernel<<<conv_blocks, blk256, 0, stream>>>(qraw, cq, spar);  // qv
    conv_res_kernel<<<conv_blocks, blk256, 0, stream>>>(kraw, ck, qraw);  // kv
    conv_res_kernel<<<conv_blocks, blk256, 0, stream>>>(vraw, cv, kraw);  // vv

    // lr path (f32, N=32)
    gemm_nt_f32<<<gemm_grid_lr, blk256, 0, stream>>>(hid, Wlr, lrpre, TOK, 32, DIM);
    lrmean_kernel<<<(BATCH * NC * NH * 2 + 255) / 256, blk256, 0, stream>>>(lrpre, lrm);

    // fast-weight state scan + attention (og written in-place into qv)
    state_scan_kernel<<<BATCH * NH, 64, 0, stream>>>(kv, vv, lrm, wini, wouti, wsti, wsto);
    attn_kernel<<<BATCH * NH * NC, 64, 0, stream>>>(qv, kv, vv, wsti, wsto,
                                                    gatb, lng, lnb, qv);

    // output projection: (o*gate) @ Wo^T
    // split(qv->Abuf) consumes qv BEFORE split(Wo->Bbuf) overwrites the region
    split_bf16_kernel<<<TOK, blk256, 0, stream>>>(qv, Abuf, TOK, 0);
    split_bf16_kernel<<<1024, blk256, 0, stream>>>(Wo, Bbuf, 1024, 1);
    gemm_mfma_bt<<<out_grid, blk256, 0, stream>>>(Abuf, Bbuf, out, TOK, DIM);
}

// Round 7
// 917.751 us; speedup vs baseline: 1.1770x; 1.0705x over previous
//
#include <hip/hip_runtime.h>
#include <hip/hip_bf16.h>
#include <math.h>

// Problem constants
#define BATCH 4
#define SEQ   2048
#define DIM   1024
#define NH    16
#define DQK   64
#define DV    64
#define DIN   4
#define CHUNK 16
#define NC    128          // SEQ / CHUNK
#define KS    4
#define TOK   (BATCH*SEQ)  // 8192
#define SCALE 0.125f       // 1/sqrt(64)
#define BASE_LR 1e-3f
#define LN_EPS 1e-5f
#define K3    3072         // split-GEMM inner dim: [hi|hi|lo] x [hi|lo|hi]

typedef float f32x4 __attribute__((ext_vector_type(4)));
typedef short s16x8 __attribute__((ext_vector_type(8)));

// ---------------------------------------------------------------------------
// bf16 helpers (bit-level, no header-type dependence)
// ---------------------------------------------------------------------------
__device__ __forceinline__ unsigned short f2bf(float f) {
    unsigned u = __float_as_uint(f);
    u += 0x7fffu + ((u >> 16) & 1u);           // round-to-nearest-even
    return (unsigned short)(u >> 16);
}
__device__ __forceinline__ float bf2f(unsigned short h) {
    return __uint_as_float(((unsigned)h) << 16);
}

__device__ __forceinline__ void gload_lds16(const void* g, void* l) {
    __builtin_amdgcn_global_load_lds(
        (const __attribute__((address_space(1))) void*)g,
        (__attribute__((address_space(3))) void*)l, 16, 0, 0);
}

// ---------------------------------------------------------------------------
// Split f32 -> bf16 hi/lo, concatenated along K.
// wmode 0 (A side): cols [0,1024)=hi [1024,2048)=hi [2048,3072)=lo
// wmode 1 (B side): cols [0,1024)=hi [1024,2048)=lo [2048,3072)=hi
// ---------------------------------------------------------------------------
__global__ __launch_bounds__(256) void split_bf16_kernel(
    const float* __restrict__ X, unsigned short* __restrict__ Y,
    int rows, int wmode)
{
    const int idx = blockIdx.x * 256 + threadIdx.x;
    if (idx >= rows * (DIM / 4)) return;
    const int r  = idx >> 8;          // DIM/4 = 256 groups per row
    const int c4 = (idx & 255) << 2;

    float4 x = *(const float4*)(X + (size_t)r * DIM + c4);
    ushort4 hv, lv;
    hv.x = f2bf(x.x); lv.x = f2bf(x.x - bf2f(hv.x));
    hv.y = f2bf(x.y); lv.y = f2bf(x.y - bf2f(hv.y));
    hv.z = f2bf(x.z); lv.z = f2bf(x.z - bf2f(hv.z));
    hv.w = f2bf(x.w); lv.w = f2bf(x.w - bf2f(hv.w));

    const size_t rb = (size_t)r * K3;
    *(ushort4*)(Y + rb + c4)        = hv;
    *(ushort4*)(Y + rb + 1024 + c4) = wmode ? lv : hv;
    *(ushort4*)(Y + rb + 2048 + c4) = wmode ? hv : lv;
}

// ---------------------------------------------------------------------------
// Fused MFMA GEMM (bf16, NT): [q|k|v|gate] = A'[8192,K3] @ B'[4096,K3]^T.
// ---------------------------------------------------------------------------
__global__ __launch_bounds__(256) void gemm_mfma_qkvg(
    const unsigned short* __restrict__ A, const unsigned short* __restrict__ B,
    float* __restrict__ Cq, float* __restrict__ Ck,
    float* __restrict__ Cv, float* __restrict__ Cg)
{
    __shared__ __align__(16) unsigned short sA[128 * 64];
    __shared__ __align__(16) unsigned short sB[128 * 64];

    const int tid  = threadIdx.x;
    const int lane = tid & 63;
    const int wav  = tid >> 6;

    // XCD-aware swizzle (nwg = 2048, multiple of 8 -> bijective)
    const int nbx = gridDim.x;                  // 32
    const int nwg = nbx * gridDim.y;            // 2048
    int flat = blockIdx.x + blockIdx.y * nbx;
    const int per = nwg >> 3;
    flat = (flat & 7) * per + (flat >> 3);
    const int m0 = (flat / nbx) * 128;
    const int n0 = (flat % nbx) * 128;          // 0..3968

    const int wm = (wav >> 1) * 64;
    const int wn = (wav & 1) * 64;

    f32x4 acc[4][4] = {};

    const int fbase = wav * 64 + lane;
    const int lrow  = lane & 15;
    const int g     = lane >> 4;

    for (int kt = 0; kt < K3; kt += 64) {
        __syncthreads();
#pragma unroll
        for (int i = 0; i < 4; ++i) {
            const int f  = fbase + i * 256;
            const int r  = f >> 3;
            const int c  = (f & 7) ^ (r & 7);
            const size_t go = (size_t)r * K3 + kt + c * 8;
            char* lb = (char*)sA + (wav * 64 + i * 256) * 16;
            gload_lds16(A + (size_t)m0 * K3 + go, lb);
        }
#pragma unroll
        for (int i = 0; i < 4; ++i) {
            const int f  = fbase + i * 256;
            const int r  = f >> 3;
            const int c  = (f & 7) ^ (r & 7);
            const size_t go = (size_t)r * K3 + kt + c * 8;
            char* lb = (char*)sB + (wav * 64 + i * 256) * 16;
            gload_lds16(B + (size_t)n0 * K3 + go, lb);
        }
        __syncthreads();

#pragma unroll
        for (int ks = 0; ks < 2; ++ks) {
            const int cbase = ks * 4 + g;
            s16x8 af[4], bfr[4];
#pragma unroll
            for (int mi = 0; mi < 4; ++mi) {
                const int r  = wm + mi * 16 + lrow;
                const int cs = cbase ^ (r & 7);
                af[mi] = *(const s16x8*)((const char*)sA + r * 128 + cs * 16);
            }
#pragma unroll
            for (int ni = 0; ni < 4; ++ni) {
                const int r  = wn + ni * 16 + lrow;
                const int cs = cbase ^ (r & 7);
                bfr[ni] = *(const s16x8*)((const char*)sB + r * 128 + cs * 16);
            }
#pragma unroll
            for (int mi = 0; mi < 4; ++mi)
#pragma unroll
                for (int ni = 0; ni < 4; ++ni)
                    acc[mi][ni] = __builtin_amdgcn_mfma_f32_16x16x32_bf16(
                        af[mi], bfr[ni], acc[mi][ni], 0, 0, 0);
        }
    }

    // epilogue: wave-uniform output-buffer select (tile never straddles 1024)
    const int nblk = n0 >> 10;
    float* __restrict__ Co = (nblk == 0) ? Cq : (nblk == 1) ? Ck
                           : (nblk == 2) ? Cv : Cg;
    const int nc0 = (n0 & 1023) + wn;
    const int lcol = lane & 15;
    const int lq   = lane >> 4;
#pragma unroll
    for (int mi = 0; mi < 4; ++mi)
#pragma unroll
        for (int ni = 0; ni < 4; ++ni)
#pragma unroll
            for (int r = 0; r < 4; ++r) {
                const int m = m0 + wm + mi * 16 + lq * 4 + r;
                const int n = nc0 + ni * 16 + lcol;
                Co[(size_t)m * DIM + n] = acc[mi][ni][r];
            }
}

// ---------------------------------------------------------------------------
// MFMA GEMM (bf16, NT), single output: used for the final Wo projection.
// ---------------------------------------------------------------------------
__global__ __launch_bounds__(256) void gemm_mfma_bt(
    const unsigned short* __restrict__ A, const unsigned short* __restrict__ B,
    float* __restrict__ C, int M, int N)
{
    __shared__ __align__(16) unsigned short sA[128 * 64];
    __shared__ __align__(16) unsigned short sB[128 * 64];

    const int tid  = threadIdx.x;
    const int lane = tid & 63;
    const int wav  = tid >> 6;

    const int nbx = gridDim.x;
    const int nwg = nbx * gridDim.y;
    int flat = blockIdx.x + blockIdx.y * nbx;
    const int per = nwg >> 3;
    flat = (flat & 7) * per + (flat >> 3);
    const int m0 = (flat / nbx) * 128;
    const int n0 = (flat % nbx) * 128;

    const int wm = (wav >> 1) * 64;
    const int wn = (wav & 1) * 64;

    f32x4 acc[4][4] = {};

    const int fbase = wav * 64 + lane;
    const int lrow  = lane & 15;
    const int g     = lane >> 4;

    for (int kt = 0; kt < K3; kt += 64) {
        __syncthreads();
#pragma unroll
        for (int i = 0; i < 4; ++i) {
            const int f  = fbase + i * 256;
            const int r  = f >> 3;
            const int c  = (f & 7) ^ (r & 7);
            const size_t go = (size_t)r * K3 + kt + c * 8;
            char* lb = (char*)sA + (wav * 64 + i * 256) * 16;
            gload_lds16(A + (size_t)m0 * K3 + go, lb);
        }
#pragma unroll
        for (int i = 0; i < 4; ++i) {
            const int f  = fbase + i * 256;
            const int r  = f >> 3;
            const int c  = (f & 7) ^ (r & 7);
            const size_t go = (size_t)r * K3 + kt + c * 8;
            char* lb = (char*)sB + (wav * 64 + i * 256) * 16;
            gload_lds16(B + (size_t)n0 * K3 + go, lb);
        }
        __syncthreads();

#pragma unroll
        for (int ks = 0; ks < 2; ++ks) {
            const int cbase = ks * 4 + g;
            s16x8 af[4], bfr[4];
#pragma unroll
            for (int mi = 0; mi < 4; ++mi) {
                const int r  = wm + mi * 16 + lrow;
                const int cs = cbase ^ (r & 7);
                af[mi] = *(const s16x8*)((const char*)sA + r * 128 + cs * 16);
            }
#pragma unroll
            for (int ni = 0; ni < 4; ++ni) {
                const int r  = wn + ni * 16 + lrow;
                const int cs = cbase ^ (r & 7);
                bfr[ni] = *(const s16x8*)((const char*)sB + r * 128 + cs * 16);
            }
#pragma unroll
            for (int mi = 0; mi < 4; ++mi)
#pragma unroll
                for (int ni = 0; ni < 4; ++ni)
                    acc[mi][ni] = __builtin_amdgcn_mfma_f32_16x16x32_bf16(
                        af[mi], bfr[ni], acc[mi][ni], 0, 0, 0);
        }
    }

    const int lcol = lane & 15;
    const int lq   = lane >> 4;
#pragma unroll
    for (int mi = 0; mi < 4; ++mi)
#pragma unroll
        for (int ni = 0; ni < 4; ++ni)
#pragma unroll
            for (int r = 0; r < 4; ++r) {
                const int m = m0 + wm + mi * 16 + lq * 4 + r;
                const int n = n0 + wn + ni * 16 + lcol;
                C[(size_t)m * N + n] = acc[mi][ni][r];
            }
}

// ---------------------------------------------------------------------------
// f32 GEMM (NT) — kept for the lr projection only (N=32).
// ---------------------------------------------------------------------------
#define GBM 128
#define GBN 128
#define GBK 8

__global__ __launch_bounds__(256) void gemm_nt_f32(
    const float* __restrict__ A, const float* __restrict__ B,
    float* __restrict__ C, int M, int N, int K)
{
    __shared__ float As[GBK][GBM + 4];
    __shared__ float Bs[GBK][GBN + 4];

    const int tid = threadIdx.x;
    const int m0 = blockIdx.y * GBM;
    const int n0 = blockIdx.x * GBN;
    const int la_m = tid >> 1;
    const int la_k = (tid & 1) << 2;
    const int tm = tid >> 4;
    const int tn = tid & 15;

    float acc[8][8] = {};

    const float* Arow = A + (size_t)(m0 + la_m) * K + la_k;
    const float* Brow = B + (size_t)(n0 + la_m) * K + la_k;
    const bool bvalid = (n0 + la_m) < N;

    for (int k0 = 0; k0 < K; k0 += GBK) {
        float4 av = *(const float4*)(Arow + k0);
        float4 bv = make_float4(0.f, 0.f, 0.f, 0.f);
        if (bvalid) bv = *(const float4*)(Brow + k0);

        __syncthreads();
        As[la_k + 0][la_m] = av.x; As[la_k + 1][la_m] = av.y;
        As[la_k + 2][la_m] = av.z; As[la_k + 3][la_m] = av.w;
        Bs[la_k + 0][la_m] = bv.x; Bs[la_k + 1][la_m] = bv.y;
        Bs[la_k + 2][la_m] = bv.z; Bs[la_k + 3][la_m] = bv.w;
        __syncthreads();

#pragma unroll
        for (int k = 0; k < GBK; ++k) {
            float4 a0 = *(const float4*)&As[k][tm * 8];
            float4 a1 = *(const float4*)&As[k][tm * 8 + 4];
            float4 b0 = *(const float4*)&Bs[k][tn * 8];
            float4 b1 = *(const float4*)&Bs[k][tn * 8 + 4];
            float a[8] = {a0.x, a0.y, a0.z, a0.w, a1.x, a1.y, a1.z, a1.w};
            float b[8] = {b0.x, b0.y, b0.z, b0.w, b1.x, b1.y, b1.z, b1.w};
#pragma unroll
            for (int i = 0; i < 8; ++i)
#pragma unroll
                for (int j = 0; j < 8; ++j)
                    acc[i][j] += a[i] * b[j];
        }
    }

#pragma unroll
    for (int i = 0; i < 8; ++i) {
        const int m = m0 + tm * 8 + i;
#pragma unroll
        for (int j = 0; j < 8; ++j) {
            const int n = n0 + tn * 8 + j;
            if (n < N) C[(size_t)m * N + n] = acc[i][j];
        }
    }
}

// ---------------------------------------------------------------------------
// Causal depthwise conv (KS=4) + identity residual.
// ---------------------------------------------------------------------------
__global__ __launch_bounds__(256) void conv_res_kernel(
    const float* __restrict__ x, const float* __restrict__ w,
    float* __restrict__ y)
{
    const int tid = blockIdx.x * blockDim.x + threadIdx.x;
    if (tid >= TOK * 256) return;
    const int c4  = (tid & 255) << 2;
    const int row = tid >> 8;
    const int t   = row & (SEQ - 1);

    const float* xp = x + (size_t)row * DIM + c4;
    float4 acc = *(const float4*)xp;      // residual
    float4 w0 = *(const float4*)(w + (c4 + 0) * 4);
    float4 w1 = *(const float4*)(w + (c4 + 1) * 4);
    float4 w2 = *(const float4*)(w + (c4 + 2) * 4);
    float4 w3 = *(const float4*)(w + (c4 + 3) * 4);

#pragma unroll
    for (int j = 0; j < 4; ++j) {
        const int tt = t - 3 + j;
        if (tt >= 0) {
            float4 xv = *(const float4*)(xp + (j - 3) * DIM);
            acc.x += xv.x * ((&w0.x)[j]);
            acc.y += xv.y * ((&w1.x)[j]);
            acc.z += xv.z * ((&w2.x)[j]);
            acc.w += xv.w * ((&w3.x)[j]);
        }
    }
    *(float4*)(y + (size_t)row * DIM + c4) = acc;
}

// ---------------------------------------------------------------------------
// lr chunk means: lrpre [B, SEQ, 32] -> lrm [B, NC, NH, 2]
// ---------------------------------------------------------------------------
__global__ __launch_bounds__(256) void lrmean_kernel(
    const float* __restrict__ lrpre, float* __restrict__ lrm)
{
    const int idx = blockIdx.x * blockDim.x + threadIdx.x;
    if (idx >= BATCH * NC * NH * 2) return;
    const int j = idx & 1;
    const int h = (idx >> 1) & 15;
    const int c = (idx >> 5) & 127;
    const int b = idx >> 12;

    float s = 0.f;
#pragma unroll
    for (int i = 0; i < CHUNK; ++i) {
        float x = lrpre[((size_t)b * SEQ + c * CHUNK + i) * 32 + h * 2 + j] + BASE_LR;
        s += fmaxf(x, 0.f) + log1pf(expf(-fabsf(x)));   // stable softplus
    }
    lrm[idx] = s * (1.f / CHUNK);
}

// ---------------------------------------------------------------------------
// Pass 1 (round-7 rewrite): 2-wave role-split scan. Block = 128 threads.
//   wave0 (tid<64):  owns W_in + k. Stages sK/sW, computes g-dot (tree),
//                    both softmaxes (sqrt trick: e2 = sqrt(e1)), writes sP.
//   wave1 (tid>=64): owns W_out + v. Prefetches v, stores its snapshots,
//                    updates W_out from sP1.
// Sync: raw s_barrier + lgkmcnt(0)-only waits (no vmcnt drain -> prefetch
// stays in flight). sP double-buffered by step parity -> 1 barrier/step.
// The scan was ISSUE-bound at 1 wave (r6: 2.1us/step ~ 4200cy); this halves
// the per-wave stream and shortens the dependent chain.
// ---------------------------------------------------------------------------
__global__ __launch_bounds__(128) void state_scan_kernel(
    const float* __restrict__ kconv, const float* __restrict__ vconv,
    const float* __restrict__ lrm,
    const float* __restrict__ win_init, const float* __restrict__ wout_init,
    float* __restrict__ wst_in, float* __restrict__ wst_out)
{
    const int bh  = blockIdx.x;
    const int b   = bh >> 4, h = bh & 15;
    const int tid = threadIdx.x;
    const int wv  = tid >> 6;          // 0 = k/W_in wave, 1 = v/W_out wave
    const int d   = tid & 63;

    __shared__ __align__(16) float sW[DIN][68];
    __shared__ __align__(16) float sK[CHUNK][68];
    __shared__ __align__(16) float sP1[2][DIN][16];
    __shared__ __align__(16) float sP2[2][DIN][16];
    __shared__ float sLR[NC * 2];

    const float* __restrict__ xin  = wv ? vconv     : kconv;
    const float* __restrict__ wini = wv ? wout_init : win_init;
    float*       __restrict__ wst  = wv ? wst_out   : wst_in;

    float W[DIN];
#pragma unroll
    for (int n = 0; n < DIN; ++n) W[n] = wini[(n * NH + h) * 64 + d];

    // preload lr means: thread t covers chunk t (j = 0,1); 128 threads = NC
    sLR[tid * 2 + 0] = lrm[(((size_t)b * NC + tid) * NH + h) * 2 + 0];
    sLR[tid * 2 + 1] = lrm[(((size_t)b * NC + tid) * NH + h) * 2 + 1];

    const int gn = d >> 4;   // 0..3  : W_in row for the g-dot (wave0)
    const int gc = d & 15;   // 0..15 : chunk column (wave0)

    float xa[CHUNK], xb[CHUNK];        // this wave's k or v chunk (dbuf)
    const size_t base00 = (size_t)b * SEQ * DIM + h * 64 + d;
#pragma unroll
    for (int i = 0; i < CHUNK; ++i) xa[i] = xin[base00 + (size_t)i * DIM];
    asm volatile("s_waitcnt lgkmcnt(0)" ::: "memory");   // sLR writes done

#define SCAN_STEP(c, XA, XB)                                                   \
    {                                                                          \
        const int pb = (c) & 1;                                                \
        if ((c) + 1 < NC) {                                                    \
            const size_t basen = base00 + (size_t)(((c) + 1) * CHUNK) * DIM;   \
            _Pragma("unroll")                                                  \
            for (int i = 0; i < CHUNK; ++i)                                    \
                XB[i] = xin[basen + (size_t)i * DIM];                          \
        }                                                                      \
        const size_t wofs = (((size_t)bh * NC + (c)) * DIN) * 64 + d;          \
        _Pragma("unroll")                                                      \
        for (int n = 0; n < DIN; ++n) wst[wofs + n * 64] = W[n];               \
        if (wv == 0) {                                                         \
            _Pragma("unroll")                                                  \
            for (int i = 0; i < CHUNK; ++i) sK[i][d] = XA[i];                  \
            _Pragma("unroll")                                                  \
            for (int n = 0; n < DIN; ++n) sW[n][d] = W[n];                     \
            asm volatile("s_waitcnt lgkmcnt(0)" ::: "memory");                 \
            float p0 = 0.f, p1 = 0.f, p2 = 0.f, p3 = 0.f;                      \
            _Pragma("unroll")                                                  \
            for (int q = 0; q < 4; ++q) {                                      \
                const int o = q * 16;                                          \
                float4 w0 = *(const float4*)&sW[gn][o + 0];                    \
                float4 k0 = *(const float4*)&sK[gc][o + 0];                    \
                float4 w1 = *(const float4*)&sW[gn][o + 4];                    \
                float4 k1 = *(const float4*)&sK[gc][o + 4];                    \
                float4 w2 = *(const float4*)&sW[gn][o + 8];                    \
                float4 k2 = *(const float4*)&sK[gc][o + 8];                    \
                float4 w3 = *(const float4*)&sW[gn][o + 12];                   \
                float4 k3 = *(const float4*)&sK[gc][o + 12];                   \
                p0 += w0.x*k0.x; p0 += w0.y*k0.y; p0 += w0.z*k0.z; p0 += w0.w*k0.w; \
                p1 += w1.x*k1.x; p1 += w1.y*k1.y; p1 += w1.z*k1.z; p1 += w1.w*k1.w; \
                p2 += w2.x*k2.x; p2 += w2.y*k2.y; p2 += w2.z*k2.z; p2 += w2.w*k2.w; \
                p3 += w3.x*k3.x; p3 += w3.y*k3.y; p3 += w3.z*k3.z; p3 += w3.w*k3.w; \
            }                                                                  \
            const float g1 = ((p0 + p1) + (p2 + p3)) * SCALE;                  \
            float m = g1;                                                      \
            _Pragma("unroll")                                                  \
            for (int mk = 8; mk >= 1; mk >>= 1)                                \
                m = fmaxf(m, __shfl_xor(m, mk, 16));                           \
            const float e1 = expf(g1 - m);                                     \
            const float rr = sqrtf(e1);   /* = exp(g1/2 - m/2) */              \
            float s1 = e1, s2 = rr;                                            \
            _Pragma("unroll")                                                  \
            for (int mk = 8; mk >= 1; mk >>= 1) {                              \
                s1 += __shfl_xor(s1, mk, 16);                                  \
                s2 += __shfl_xor(s2, mk, 16);                                  \
            }                                                                  \
            sP1[pb][gn][gc] = e1 / s1;                                         \
            sP2[pb][gn][gc] = rr / s2;                                         \
            asm volatile("s_waitcnt lgkmcnt(0)" ::: "memory");                 \
        }                                                                      \
        __builtin_amdgcn_s_barrier();                                          \
        const float lr = sLR[(c) * 2 + wv];                                    \
        const float (*P)[16] = wv ? sP1[pb] : sP2[pb];                         \
        _Pragma("unroll")                                                      \
        for (int n = 0; n < DIN; ++n) {                                        \
            float4 q0 = *(const float4*)&P[n][0];                              \
            float4 q1 = *(const float4*)&P[n][4];                              \
            float4 q2 = *(const float4*)&P[n][8];                              \
            float4 q3 = *(const float4*)&P[n][12];                             \
            float t0 = q0.x*XA[0];  t0 += q0.y*XA[1];                          \
            t0 += q0.z*XA[2];       t0 += q0.w*XA[3];                          \
            float t1 = q1.x*XA[4];  t1 += q1.y*XA[5];                          \
            t1 += q1.z*XA[6];       t1 += q1.w*XA[7];                          \
            float t2 = q2.x*XA[8];  t2 += q2.y*XA[9];                          \
            t2 += q2.z*XA[10];      t2 += q2.w*XA[11];                         \
            float t3 = q3.x*XA[12]; t3 += q3.y*XA[13];                         \
            t3 += q3.z*XA[14];      t3 += q3.w*XA[15];                         \
            W[n] += lr * ((t0 + t1) + (t2 + t3));                              \
        }                                                                      \
    }

    for (int c = 0; c < NC; c += 2) {
        SCAN_STEP(c,     xa, xb);
        SCAN_STEP(c + 1, xb, xa);
    }
#undef SCAN_STEP
}

// ---------------------------------------------------------------------------
// Pass 2: per-(b,h,chunk) attention + LayerNorm + gate.
// og may alias qconv: each block loads its full q-slice into LDS before
// writing the identical og slice (block-local, race-free).
// ---------------------------------------------------------------------------
__global__ __launch_bounds__(64) void attn_kernel(
    const float* __restrict__ qconv, const float* __restrict__ kconv,
    const float* __restrict__ vconv,
    const float* __restrict__ wst_in, const float* __restrict__ wst_out,
    const float* __restrict__ gate,
    const float* __restrict__ gamma, const float* __restrict__ beta,
    float* __restrict__ og)
{
    const int blk = blockIdx.x;
    const int c  = blk & (NC - 1);
    const int bh = blk >> 7;
    const int h = bh & 15, b = bh >> 4;
    const int d = threadIdx.x;

    __shared__ float sQ[CHUNK][65];
    __shared__ float sKf[DIN + CHUNK][65];
    __shared__ float sS[CHUNK][21];
    __shared__ float sO[CHUNK][65];
    __shared__ float sMu[CHUNK], sRs[CHUNK];

    float vf[DIN + CHUNK];

    const size_t wofs = (size_t)blk * (DIN * 64) + d;
#pragma unroll
    for (int n = 0; n < DIN; ++n) {
        sKf[n][d] = wst_in [wofs + n * 64];
        vf[n]     = wst_out[wofs + n * 64];
    }
    const size_t base = ((size_t)b * SEQ + c * CHUNK) * DIM + h * 64 + d;
#pragma unroll
    for (int i = 0; i < CHUNK; ++i) {
        sQ[i][d]        = qconv[base + (size_t)i * DIM];
        sKf[DIN + i][d] = kconv[base + (size_t)i * DIM];
        vf[DIN + i]     = vconv[base + (size_t)i * DIM];
    }
    __syncthreads();

#pragma unroll
    for (int r = 0; r < 5; ++r) {
        const int p = d + 64 * r;
        const int t = p / 20, j = p % 20;
        float dot = 0.f;
#pragma unroll
        for (int dd = 0; dd < 64; ++dd) dot += sQ[t][dd] * sKf[j][dd];
        float s = dot * SCALE;
        if (j >= DIN && (j - DIN) > t) s = -3.0e38f;
        sS[t][j] = s;
    }
    __syncthreads();

    if (d < CHUNK) {
        float m = -3.0e38f;
#pragma unroll
        for (int j = 0; j < DIN + CHUNK; ++j) m = fmaxf(m, sS[d][j]);
        float e[DIN + CHUNK];
        float sum = 0.f;
#pragma unroll
        for (int j = 0; j < DIN + CHUNK; ++j) { e[j] = expf(sS[d][j] - m); sum += e[j]; }
        const float inv = 1.f / sum;
#pragma unroll
        for (int j = 0; j < DIN + CHUNK; ++j) sS[d][j] = e[j] * inv;
    }
    __syncthreads();

#pragma unroll
    for (int t = 0; t < CHUNK; ++t) {
        float o = 0.f;
#pragma unroll
        for (int j = 0; j < DIN + CHUNK; ++j) o += sS[t][j] * vf[j];
        sO[t][d] = o;
    }
    __syncthreads();

    if (d < CHUNK) {
        float su = 0.f, sq = 0.f;
#pragma unroll
        for (int dd = 0; dd < 64; ++dd) { float x = sO[d][dd]; su += x; sq += x * x; }
        float mu = su * (1.f / 64.f);
        float var = sq * (1.f / 64.f) - mu * mu;
        sMu[d] = mu;
        sRs[d] = rsqrtf(var + LN_EPS);
    }
    __syncthreads();

    const float gm = gamma[d], bt = beta[d];
#pragma unroll
    for (int t = 0; t < CHUNK; ++t) {
        float val = (sO[t][d] - sMu[t]) * sRs[t] * gm + bt;
        float gval = gate[base + (size_t)t * DIM];
        og[base + (size_t)t * DIM] = val * gval;
    }
}

// ---------------------------------------------------------------------------
// Workspace layout (high-water ~236.4 MB; round-2's 242.2 MB layout passed):
//   qraw kraw vraw gatb (4x 33.55 MB f32)
//   lrpre (1 MB)  lrm  wsti wsto (16.8 MB)
//   Abuf (50.3 MB bf16)
//   Bbuf (25.2 MB bf16)  <-- ALIASED by spar (33.55 MB f32)
// spar/Bbuf lifetime disjointness: all dispatches serialized on one stream.
// ---------------------------------------------------------------------------
extern "C" void kernel_launch(void* const* d_in, const int* in_sizes, int n_in,
                              void* d_out, int out_size, void* d_ws, size_t ws_size,
                              hipStream_t stream)
{
    const float* hid   = (const float*)d_in[0];
    const float* Wq    = (const float*)d_in[1];
    const float* Wk    = (const float*)d_in[2];
    const float* Wv    = (const float*)d_in[3];
    const float* Wlr   = (const float*)d_in[4];
    const float* Wo    = (const float*)d_in[5];
    const float* Wg    = (const float*)d_in[6];
    const float* cq    = (const float*)d_in[7];
    const float* ck    = (const float*)d_in[8];
    const float* cv    = (const float*)d_in[9];
    const float* wini  = (const float*)d_in[10];
    const float* wouti = (const float*)d_in[11];
    const float* lng   = (const float*)d_in[12];
    const float* lnb   = (const float*)d_in[13];
    float* out = (float*)d_out;

    float* ws = (float*)d_ws;
    const size_t DSZ = (size_t)TOK * DIM;
    float* qraw  = ws;
    float* kraw  = qraw + DSZ;
    float* vraw  = kraw + DSZ;
    float* gatb  = vraw + DSZ;
    float* lrpre = gatb + DSZ;                         // TOK*32
    float* lrm   = lrpre + (size_t)TOK * 32;           // 16384
    float* wsti  = lrm   + BATCH * NC * NH * 2;
    float* wsto  = wsti  + (size_t)BATCH * NH * NC * DIN * 64;
    unsigned short* Abuf = (unsigned short*)(wsto + (size_t)BATCH * NH * NC * DIN * 64);
    unsigned short* Bbuf = Abuf + (size_t)TOK * K3;    // [4096][K3]
    float* spar = (float*)Bbuf;        // aliases Bbuf (disjoint lifetimes)

    // buffer ping-pong: qv = spar, kv = qraw, vv = kraw (after convs)
    float* qv = spar;
    float* kv = qraw;
    float* vv = kraw;

    const dim3 blk256(256);
    const dim3 fused_grid(32, 64);                     // N=4096 tiles x M tiles
    const dim3 out_grid(8, 64);                        // final Wo GEMM
    const dim3 gemm_grid_lr(1, TOK / GBM);
    const int conv_blocks = (TOK * 256 + 255) / 256;

    // splits: hidden -> Abuf; 4 weights -> Bbuf row blocks
    split_bf16_kernel<<<TOK, blk256, 0, stream>>>(hid, Abuf, TOK, 0);
    split_bf16_kernel<<<1024, blk256, 0, stream>>>(Wq, Bbuf,                       1024, 1);
    split_bf16_kernel<<<1024, blk256, 0, stream>>>(Wk, Bbuf + (size_t)1024 * K3,   1024, 1);
    split_bf16_kernel<<<1024, blk256, 0, stream>>>(Wv, Bbuf + (size_t)2048 * K3,   1024, 1);
    split_bf16_kernel<<<1024, blk256, 0, stream>>>(Wg, Bbuf + (size_t)3072 * K3,   1024, 1);

    // fused q/k/v/gate projection
    gemm_mfma_qkvg<<<fused_grid, blk256, 0, stream>>>(Abuf, Bbuf, qraw, kraw, vraw, gatb);

    // convs (ordering matters: each reads the buffer the next one overwrites;
    // conv-q's write to spar retires Bbuf)
    conv_res_kernel<<<conv_blocks, blk256, 0, stream>>>(qraw, cq, spar);  // qv
    conv_res_kernel<<<conv_blocks, blk256, 0, stream>>>(kraw, ck, qraw);  // kv
    conv_res_kernel<<<conv_blocks, blk256, 0, stream>>>(vraw, cv, kraw);  // vv

    // lr path (f32, N=32)
    gemm_nt_f32<<<gemm_grid_lr, blk256, 0, stream>>>(hid, Wlr, lrpre, TOK, 32, DIM);
    lrmean_kernel<<<(BATCH * NC * NH * 2 + 255) / 256, blk256, 0, stream>>>(lrpre, lrm);

    // fast-weight state scan (2-wave blocks) + attention
    state_scan_kernel<<<BATCH * NH, 128, 0, stream>>>(kv, vv, lrm, wini, wouti, wsti, wsto);
    attn_kernel<<<BATCH * NH * NC, 64, 0, stream>>>(qv, kv, vv, wsti, wsto,
                                                    gatb, lng, lnb, qv);

    // output projection: (o*gate) @ Wo^T
    // split(qv->Abuf) consumes qv BEFORE split(Wo->Bbuf) overwrites the region
    split_bf16_kernel<<<TOK, blk256, 0, stream>>>(qv, Abuf, TOK, 0);
    split_bf16_kernel<<<1024, blk256, 0, stream>>>(Wo, Bbuf, 1024, 1);
    gemm_mfma_bt<<<out_grid, blk256, 0, stream>>>(Abuf, Bbuf, out, TOK, DIM);
}

// Round 8
// 886.055 us; speedup vs baseline: 1.2191x; 1.0358x over previous
//
#include <hip/hip_runtime.h>
#include <hip/hip_bf16.h>
#include <math.h>

// Problem constants
#define BATCH 4
#define SEQ   2048
#define DIM   1024
#define NH    16
#define DQK   64
#define DV    64
#define DIN   4
#define CHUNK 16
#define NC    128          // SEQ / CHUNK
#define KS    4
#define TOK   (BATCH*SEQ)  // 8192
#define SCALE 0.125f       // 1/sqrt(64)
#define BASE_LR 1e-3f
#define LN_EPS 1e-5f
#define K3    3072         // split-GEMM inner dim: [hi|hi|lo] x [hi|lo|hi]

typedef float f32x4 __attribute__((ext_vector_type(4)));
typedef short s16x8 __attribute__((ext_vector_type(8)));

// ---------------------------------------------------------------------------
// bf16 helpers (bit-level, no header-type dependence)
// ---------------------------------------------------------------------------
__device__ __forceinline__ unsigned short f2bf(float f) {
    unsigned u = __float_as_uint(f);
    u += 0x7fffu + ((u >> 16) & 1u);           // round-to-nearest-even
    return (unsigned short)(u >> 16);
}
__device__ __forceinline__ float bf2f(unsigned short h) {
    return __uint_as_float(((unsigned)h) << 16);
}

__device__ __forceinline__ void gload_lds16(const void* g, void* l) {
    __builtin_amdgcn_global_load_lds(
        (const __attribute__((address_space(1))) void*)g,
        (__attribute__((address_space(3))) void*)l, 16, 0, 0);
}

// ---------------------------------------------------------------------------
// Split f32 -> bf16 hi/lo, concatenated along K.
// wmode 0 (A side): cols [0,1024)=hi [1024,2048)=hi [2048,3072)=lo
// wmode 1 (B side): cols [0,1024)=hi [1024,2048)=lo [2048,3072)=hi
// ---------------------------------------------------------------------------
__global__ __launch_bounds__(256) void split_bf16_kernel(
    const float* __restrict__ X, unsigned short* __restrict__ Y,
    int rows, int wmode)
{
    const int idx = blockIdx.x * 256 + threadIdx.x;
    if (idx >= rows * (DIM / 4)) return;
    const int r  = idx >> 8;          // DIM/4 = 256 groups per row
    const int c4 = (idx & 255) << 2;

    float4 x = *(const float4*)(X + (size_t)r * DIM + c4);
    ushort4 hv, lv;
    hv.x = f2bf(x.x); lv.x = f2bf(x.x - bf2f(hv.x));
    hv.y = f2bf(x.y); lv.y = f2bf(x.y - bf2f(hv.y));
    hv.z = f2bf(x.z); lv.z = f2bf(x.z - bf2f(hv.z));
    hv.w = f2bf(x.w); lv.w = f2bf(x.w - bf2f(hv.w));

    const size_t rb = (size_t)r * K3;
    *(ushort4*)(Y + rb + c4)        = hv;
    *(ushort4*)(Y + rb + 1024 + c4) = wmode ? lv : hv;
    *(ushort4*)(Y + rb + 2048 + c4) = wmode ? hv : lv;
}

// ---------------------------------------------------------------------------
// Fused MFMA GEMM (round-8 rewrite): 256x256 tile, BK=64, 8 waves (2Mx4N),
// counted-vmcnt 2-K-tile pipeline (T3+T4), setprio around MFMA (T5).
// LDS 128 KiB: sA[2]/sB[2] double-buffered by K-tile parity.
// Per K-tile t: vmcnt(8) waits tile t's 8 loads (t+1's stay IN FLIGHT across
// the barrier - never drain to 0 in steady state) -> barrier -> 24 ds_read
// + 64 MFMA -> barrier -> stage t+2 into the just-freed buffer.
// Same c^(r&7) both-sides swizzle + fragment math as before: output is
// BIT-IDENTICAL to the 128^2 version (same per-element K accumulation order).
// ---------------------------------------------------------------------------
__global__ __launch_bounds__(512, 2) void gemm_mfma_qkvg(
    const unsigned short* __restrict__ A, const unsigned short* __restrict__ B,
    float* __restrict__ Cq, float* __restrict__ Ck,
    float* __restrict__ Cv, float* __restrict__ Cg)
{
    __shared__ __align__(16) unsigned short sA[2][256 * 64];
    __shared__ __align__(16) unsigned short sB[2][256 * 64];

    const int tid  = threadIdx.x;
    const int lane = tid & 63;
    const int wid  = tid >> 6;

    // XCD swizzle: grid (16,32) -> nwg=512, %8==0 -> bijective
    const int nbx = gridDim.x;                  // 16
    const int nwg = nbx * gridDim.y;            // 512
    int flat = blockIdx.x + blockIdx.y * nbx;
    const int per = nwg >> 3;
    flat = (flat & 7) * per + (flat >> 3);
    const int m0 = (flat / nbx) * 256;
    const int n0 = (flat % nbx) * 256;

    const int wm = (wid >> 2) * 128;    // 2 M-rows of waves
    const int wn = (wid & 3) * 64;      // 4 N-cols of waves

    f32x4 acc[8][4] = {};

    const int lrow = lane & 15;
    const int g    = lane >> 4;

#define STAGE256(kt, db)                                                       \
    {                                                                          \
        _Pragma("unroll")                                                      \
        for (int i = 0; i < 4; ++i) {                                          \
            const int f = tid + i * 512;          /* 16B slot 0..2047 */       \
            const int r = f >> 3;                 /* tile row 0..255  */       \
            const int c = (f & 7) ^ (r & 7);      /* pre-swizzled src */       \
            gload_lds16(A + (size_t)(m0 + r) * K3 + (kt) * 64 + c * 8,         \
                        (char*)sA[db] + (wid * 64 + i * 512) * 16);            \
        }                                                                      \
        _Pragma("unroll")                                                      \
        for (int i = 0; i < 4; ++i) {                                          \
            const int f = tid + i * 512;                                       \
            const int r = f >> 3;                                              \
            const int c = (f & 7) ^ (r & 7);                                   \
            gload_lds16(B + (size_t)(n0 + r) * K3 + (kt) * 64 + c * 8,         \
                        (char*)sB[db] + (wid * 64 + i * 512) * 16);            \
        }                                                                      \
    }

    STAGE256(0, 0);                     // 8 loads in flight
    STAGE256(1, 1);                     // 16 in flight

    const int NT = K3 / 64;             // 48
    for (int t = 0; t < NT; ++t) {
        const int cur = t & 1;
        // wait ONLY tile t's 8 loads; tile t+1's 8 stay in flight
        if (t < NT - 1) asm volatile("s_waitcnt vmcnt(8)" ::: "memory");
        else            asm volatile("s_waitcnt vmcnt(0)" ::: "memory");
        __builtin_amdgcn_s_barrier();
        asm volatile("" ::: "memory");   // fence: no ds_read hoists above

        const unsigned short* __restrict__ pA = sA[cur];
        const unsigned short* __restrict__ pB = sB[cur];
        __builtin_amdgcn_s_setprio(1);
#pragma unroll
        for (int ks = 0; ks < 2; ++ks) {
            const int cbase = ks * 4 + g;
            s16x8 af[8], bfr[4];
#pragma unroll
            for (int mi = 0; mi < 8; ++mi) {
                const int r  = wm + mi * 16 + lrow;
                const int cs = cbase ^ (r & 7);
                af[mi] = *(const s16x8*)((const char*)pA + r * 128 + cs * 16);
            }
#pragma unroll
            for (int ni = 0; ni < 4; ++ni) {
                const int r  = wn + ni * 16 + lrow;
                const int cs = cbase ^ (r & 7);
                bfr[ni] = *(const s16x8*)((const char*)pB + r * 128 + cs * 16);
            }
#pragma unroll
            for (int mi = 0; mi < 8; ++mi)
#pragma unroll
                for (int ni = 0; ni < 4; ++ni)
                    acc[mi][ni] = __builtin_amdgcn_mfma_f32_16x16x32_bf16(
                        af[mi], bfr[ni], acc[mi][ni], 0, 0, 0);
        }
        __builtin_amdgcn_s_setprio(0);

        asm volatile("" ::: "memory");   // all reads of buf[cur] done (lgkmcnt
        __builtin_amdgcn_s_barrier();    // waited before MFMA use) block-wide
        asm volatile("" ::: "memory");
        if (t + 2 < NT) STAGE256(t + 2, cur);   // overwrite freed buffer
    }

    // epilogue: wave-uniform output select (256-tile never straddles 1024)
    const int nblk = n0 >> 10;
    float* __restrict__ Co = (nblk == 0) ? Cq : (nblk == 1) ? Ck
                           : (nblk == 2) ? Cv : Cg;
    const int nc0 = (n0 & 1023) + wn;
    const int lcol = lane & 15;
    const int lq   = lane >> 4;
#pragma unroll
    for (int mi = 0; mi < 8; ++mi)
#pragma unroll
        for (int ni = 0; ni < 4; ++ni)
#pragma unroll
            for (int r = 0; r < 4; ++r) {
                const int m = m0 + wm + mi * 16 + lq * 4 + r;
                const int n = nc0 + ni * 16 + lcol;
                Co[(size_t)m * DIM + n] = acc[mi][ni][r];
            }
#undef STAGE256
}

// ---------------------------------------------------------------------------
// MFMA GEMM (bf16, NT), single output: used for the final Wo projection.
// (unchanged 128^2 m97-structure - proven)
// ---------------------------------------------------------------------------
__global__ __launch_bounds__(256) void gemm_mfma_bt(
    const unsigned short* __restrict__ A, const unsigned short* __restrict__ B,
    float* __restrict__ C, int M, int N)
{
    __shared__ __align__(16) unsigned short sA[128 * 64];
    __shared__ __align__(16) unsigned short sB[128 * 64];

    const int tid  = threadIdx.x;
    const int lane = tid & 63;
    const int wav  = tid >> 6;

    const int nbx = gridDim.x;
    const int nwg = nbx * gridDim.y;
    int flat = blockIdx.x + blockIdx.y * nbx;
    const int per = nwg >> 3;
    flat = (flat & 7) * per + (flat >> 3);
    const int m0 = (flat / nbx) * 128;
    const int n0 = (flat % nbx) * 128;

    const int wm = (wav >> 1) * 64;
    const int wn = (wav & 1) * 64;

    f32x4 acc[4][4] = {};

    const int fbase = wav * 64 + lane;
    const int lrow  = lane & 15;
    const int g     = lane >> 4;

    for (int kt = 0; kt < K3; kt += 64) {
        __syncthreads();
#pragma unroll
        for (int i = 0; i < 4; ++i) {
            const int f  = fbase + i * 256;
            const int r  = f >> 3;
            const int c  = (f & 7) ^ (r & 7);
            const size_t go = (size_t)r * K3 + kt + c * 8;
            char* lb = (char*)sA + (wav * 64 + i * 256) * 16;
            gload_lds16(A + (size_t)m0 * K3 + go, lb);
        }
#pragma unroll
        for (int i = 0; i < 4; ++i) {
            const int f  = fbase + i * 256;
            const int r  = f >> 3;
            const int c  = (f & 7) ^ (r & 7);
            const size_t go = (size_t)r * K3 + kt + c * 8;
            char* lb = (char*)sB + (wav * 64 + i * 256) * 16;
            gload_lds16(B + (size_t)n0 * K3 + go, lb);
        }
        __syncthreads();

#pragma unroll
        for (int ks = 0; ks < 2; ++ks) {
            const int cbase = ks * 4 + g;
            s16x8 af[4], bfr[4];
#pragma unroll
            for (int mi = 0; mi < 4; ++mi) {
                const int r  = wm + mi * 16 + lrow;
                const int cs = cbase ^ (r & 7);
                af[mi] = *(const s16x8*)((const char*)sA + r * 128 + cs * 16);
            }
#pragma unroll
            for (int ni = 0; ni < 4; ++ni) {
                const int r  = wn + ni * 16 + lrow;
                const int cs = cbase ^ (r & 7);
                bfr[ni] = *(const s16x8*)((const char*)sB + r * 128 + cs * 16);
            }
#pragma unroll
            for (int mi = 0; mi < 4; ++mi)
#pragma unroll
                for (int ni = 0; ni < 4; ++ni)
                    acc[mi][ni] = __builtin_amdgcn_mfma_f32_16x16x32_bf16(
                        af[mi], bfr[ni], acc[mi][ni], 0, 0, 0);
        }
    }

    const int lcol = lane & 15;
    const int lq   = lane >> 4;
#pragma unroll
    for (int mi = 0; mi < 4; ++mi)
#pragma unroll
        for (int ni = 0; ni < 4; ++ni)
#pragma unroll
            for (int r = 0; r < 4; ++r) {
                const int m = m0 + wm + mi * 16 + lq * 4 + r;
                const int n = n0 + wn + ni * 16 + lcol;
                C[(size_t)m * N + n] = acc[mi][ni][r];
            }
}

// ---------------------------------------------------------------------------
// f32 GEMM (NT) — kept for the lr projection only (N=32).
// ---------------------------------------------------------------------------
#define GBM 128
#define GBN 128
#define GBK 8

__global__ __launch_bounds__(256) void gemm_nt_f32(
    const float* __restrict__ A, const float* __restrict__ B,
    float* __restrict__ C, int M, int N, int K)
{
    __shared__ float As[GBK][GBM + 4];
    __shared__ float Bs[GBK][GBN + 4];

    const int tid = threadIdx.x;
    const int m0 = blockIdx.y * GBM;
    const int n0 = blockIdx.x * GBN;
    const int la_m = tid >> 1;
    const int la_k = (tid & 1) << 2;
    const int tm = tid >> 4;
    const int tn = tid & 15;

    float acc[8][8] = {};

    const float* Arow = A + (size_t)(m0 + la_m) * K + la_k;
    const float* Brow = B + (size_t)(n0 + la_m) * K + la_k;
    const bool bvalid = (n0 + la_m) < N;

    for (int k0 = 0; k0 < K; k0 += GBK) {
        float4 av = *(const float4*)(Arow + k0);
        float4 bv = make_float4(0.f, 0.f, 0.f, 0.f);
        if (bvalid) bv = *(const float4*)(Brow + k0);

        __syncthreads();
        As[la_k + 0][la_m] = av.x; As[la_k + 1][la_m] = av.y;
        As[la_k + 2][la_m] = av.z; As[la_k + 3][la_m] = av.w;
        Bs[la_k + 0][la_m] = bv.x; Bs[la_k + 1][la_m] = bv.y;
        Bs[la_k + 2][la_m] = bv.z; Bs[la_k + 3][la_m] = bv.w;
        __syncthreads();

#pragma unroll
        for (int k = 0; k < GBK; ++k) {
            float4 a0 = *(const float4*)&As[k][tm * 8];
            float4 a1 = *(const float4*)&As[k][tm * 8 + 4];
            float4 b0 = *(const float4*)&Bs[k][tn * 8];
            float4 b1 = *(const float4*)&Bs[k][tn * 8 + 4];
            float a[8] = {a0.x, a0.y, a0.z, a0.w, a1.x, a1.y, a1.z, a1.w};
            float b[8] = {b0.x, b0.y, b0.z, b0.w, b1.x, b1.y, b1.z, b1.w};
#pragma unroll
            for (int i = 0; i < 8; ++i)
#pragma unroll
                for (int j = 0; j < 8; ++j)
                    acc[i][j] += a[i] * b[j];
        }
    }

#pragma unroll
    for (int i = 0; i < 8; ++i) {
        const int m = m0 + tm * 8 + i;
#pragma unroll
        for (int j = 0; j < 8; ++j) {
            const int n = n0 + tn * 8 + j;
            if (n < N) C[(size_t)m * N + n] = acc[i][j];
        }
    }
}

// ---------------------------------------------------------------------------
// Causal depthwise conv (KS=4) + identity residual.
// ---------------------------------------------------------------------------
__global__ __launch_bounds__(256) void conv_res_kernel(
    const float* __restrict__ x, const float* __restrict__ w,
    float* __restrict__ y)
{
    const int tid = blockIdx.x * blockDim.x + threadIdx.x;
    if (tid >= TOK * 256) return;
    const int c4  = (tid & 255) << 2;
    const int row = tid >> 8;
    const int t   = row & (SEQ - 1);

    const float* xp = x + (size_t)row * DIM + c4;
    float4 acc = *(const float4*)xp;      // residual
    float4 w0 = *(const float4*)(w + (c4 + 0) * 4);
    float4 w1 = *(const float4*)(w + (c4 + 1) * 4);
    float4 w2 = *(const float4*)(w + (c4 + 2) * 4);
    float4 w3 = *(const float4*)(w + (c4 + 3) * 4);

#pragma unroll
    for (int j = 0; j < 4; ++j) {
        const int tt = t - 3 + j;
        if (tt >= 0) {
            float4 xv = *(const float4*)(xp + (j - 3) * DIM);
            acc.x += xv.x * ((&w0.x)[j]);
            acc.y += xv.y * ((&w1.x)[j]);
            acc.z += xv.z * ((&w2.x)[j]);
            acc.w += xv.w * ((&w3.x)[j]);
        }
    }
    *(float4*)(y + (size_t)row * DIM + c4) = acc;
}

// ---------------------------------------------------------------------------
// lr chunk means: lrpre [B, SEQ, 32] -> lrm [B, NC, NH, 2]
// ---------------------------------------------------------------------------
__global__ __launch_bounds__(256) void lrmean_kernel(
    const float* __restrict__ lrpre, float* __restrict__ lrm)
{
    const int idx = blockIdx.x * blockDim.x + threadIdx.x;
    if (idx >= BATCH * NC * NH * 2) return;
    const int j = idx & 1;
    const int h = (idx >> 1) & 15;
    const int c = (idx >> 5) & 127;
    const int b = idx >> 12;

    float s = 0.f;
#pragma unroll
    for (int i = 0; i < CHUNK; ++i) {
        float x = lrpre[((size_t)b * SEQ + c * CHUNK + i) * 32 + h * 2 + j] + BASE_LR;
        s += fmaxf(x, 0.f) + log1pf(expf(-fabsf(x)));   // stable softplus
    }
    lrm[idx] = s * (1.f / CHUNK);
}

// ---------------------------------------------------------------------------
// Pass 1: 2-wave role-split scan (unchanged from round 7).
// ---------------------------------------------------------------------------
__global__ __launch_bounds__(128) void state_scan_kernel(
    const float* __restrict__ kconv, const float* __restrict__ vconv,
    const float* __restrict__ lrm,
    const float* __restrict__ win_init, const float* __restrict__ wout_init,
    float* __restrict__ wst_in, float* __restrict__ wst_out)
{
    const int bh  = blockIdx.x;
    const int b   = bh >> 4, h = bh & 15;
    const int tid = threadIdx.x;
    const int wv  = tid >> 6;          // 0 = k/W_in wave, 1 = v/W_out wave
    const int d   = tid & 63;

    __shared__ __align__(16) float sW[DIN][68];
    __shared__ __align__(16) float sK[CHUNK][68];
    __shared__ __align__(16) float sP1[2][DIN][16];
    __shared__ __align__(16) float sP2[2][DIN][16];
    __shared__ float sLR[NC * 2];

    const float* __restrict__ xin  = wv ? vconv     : kconv;
    const float* __restrict__ wini = wv ? wout_init : win_init;
    float*       __restrict__ wst  = wv ? wst_out   : wst_in;

    float W[DIN];
#pragma unroll
    for (int n = 0; n < DIN; ++n) W[n] = wini[(n * NH + h) * 64 + d];

    sLR[tid * 2 + 0] = lrm[(((size_t)b * NC + tid) * NH + h) * 2 + 0];
    sLR[tid * 2 + 1] = lrm[(((size_t)b * NC + tid) * NH + h) * 2 + 1];

    const int gn = d >> 4;
    const int gc = d & 15;

    float xa[CHUNK], xb[CHUNK];
    const size_t base00 = (size_t)b * SEQ * DIM + h * 64 + d;
#pragma unroll
    for (int i = 0; i < CHUNK; ++i) xa[i] = xin[base00 + (size_t)i * DIM];
    asm volatile("s_waitcnt lgkmcnt(0)" ::: "memory");

#define SCAN_STEP(c, XA, XB)                                                   \
    {                                                                          \
        const int pb = (c) & 1;                                                \
        if ((c) + 1 < NC) {                                                    \
            const size_t basen = base00 + (size_t)(((c) + 1) * CHUNK) * DIM;   \
            _Pragma("unroll")                                                  \
            for (int i = 0; i < CHUNK; ++i)                                    \
                XB[i] = xin[basen + (size_t)i * DIM];                          \
        }                                                                      \
        const size_t wofs = (((size_t)bh * NC + (c)) * DIN) * 64 + d;          \
        _Pragma("unroll")                                                      \
        for (int n = 0; n < DIN; ++n) wst[wofs + n * 64] = W[n];               \
        if (wv == 0) {                                                         \
            _Pragma("unroll")                                                  \
            for (int i = 0; i < CHUNK; ++i) sK[i][d] = XA[i];                  \
            _Pragma("unroll")                                                  \
            for (int n = 0; n < DIN; ++n) sW[n][d] = W[n];                     \
            asm volatile("s_waitcnt lgkmcnt(0)" ::: "memory");                 \
            float p0 = 0.f, p1 = 0.f, p2 = 0.f, p3 = 0.f;                      \
            _Pragma("unroll")                                                  \
            for (int q = 0; q < 4; ++q) {                                      \
                const int o = q * 16;                                          \
                float4 w0 = *(const float4*)&sW[gn][o + 0];                    \
                float4 k0 = *(const float4*)&sK[gc][o + 0];                    \
                float4 w1 = *(const float4*)&sW[gn][o + 4];                    \
                float4 k1 = *(const float4*)&sK[gc][o + 4];                    \
                float4 w2 = *(const float4*)&sW[gn][o + 8];                    \
                float4 k2 = *(const float4*)&sK[gc][o + 8];                    \
                float4 w3 = *(const float4*)&sW[gn][o + 12];                   \
                float4 k3 = *(const float4*)&sK[gc][o + 12];                   \
                p0 += w0.x*k0.x; p0 += w0.y*k0.y; p0 += w0.z*k0.z; p0 += w0.w*k0.w; \
                p1 += w1.x*k1.x; p1 += w1.y*k1.y; p1 += w1.z*k1.z; p1 += w1.w*k1.w; \
                p2 += w2.x*k2.x; p2 += w2.y*k2.y; p2 += w2.z*k2.z; p2 += w2.w*k2.w; \
                p3 += w3.x*k3.x; p3 += w3.y*k3.y; p3 += w3.z*k3.z; p3 += w3.w*k3.w; \
            }                                                                  \
            const float g1 = ((p0 + p1) + (p2 + p3)) * SCALE;                  \
            float m = g1;                                                      \
            _Pragma("unroll")                                                  \
            for (int mk = 8; mk >= 1; mk >>= 1)                                \
                m = fmaxf(m, __shfl_xor(m, mk, 16));                           \
            const float e1 = expf(g1 - m);                                     \
            const float rr = sqrtf(e1);   /* = exp(g1/2 - m/2) */              \
            float s1 = e1, s2 = rr;                                            \
            _Pragma("unroll")                                                  \
            for (int mk = 8; mk >= 1; mk >>= 1) {                              \
                s1 += __shfl_xor(s1, mk, 16);                                  \
                s2 += __shfl_xor(s2, mk, 16);                                  \
            }                                                                  \
            sP1[pb][gn][gc] = e1 / s1;                                         \
            sP2[pb][gn][gc] = rr / s2;                                         \
            asm volatile("s_waitcnt lgkmcnt(0)" ::: "memory");                 \
        }                                                                      \
        __builtin_amdgcn_s_barrier();                                          \
        const float lr = sLR[(c) * 2 + wv];                                    \
        const float (*P)[16] = wv ? sP1[pb] : sP2[pb];                         \
        _Pragma("unroll")                                                      \
        for (int n = 0; n < DIN; ++n) {                                        \
            float4 q0 = *(const float4*)&P[n][0];                              \
            float4 q1 = *(const float4*)&P[n][4];                              \
            float4 q2 = *(const float4*)&P[n][8];                              \
            float4 q3 = *(const float4*)&P[n][12];                             \
            float t0 = q0.x*XA[0];  t0 += q0.y*XA[1];                          \
            t0 += q0.z*XA[2];       t0 += q0.w*XA[3];                          \
            float t1 = q1.x*XA[4];  t1 += q1.y*XA[5];                          \
            t1 += q1.z*XA[6];       t1 += q1.w*XA[7];                          \
            float t2 = q2.x*XA[8];  t2 += q2.y*XA[9];                          \
            t2 += q2.z*XA[10];      t2 += q2.w*XA[11];                         \
            float t3 = q3.x*XA[12]; t3 += q3.y*XA[13];                         \
            t3 += q3.z*XA[14];      t3 += q3.w*XA[15];                         \
            W[n] += lr * ((t0 + t1) + (t2 + t3));                              \
        }                                                                      \
    }

    for (int c = 0; c < NC; c += 2) {
        SCAN_STEP(c,     xa, xb);
        SCAN_STEP(c + 1, xb, xa);
    }
#undef SCAN_STEP
}

// ---------------------------------------------------------------------------
// Pass 2: per-(b,h,chunk) attention + LayerNorm + gate (unchanged).
// ---------------------------------------------------------------------------
__global__ __launch_bounds__(64) void attn_kernel(
    const float* __restrict__ qconv, const float* __restrict__ kconv,
    const float* __restrict__ vconv,
    const float* __restrict__ wst_in, const float* __restrict__ wst_out,
    const float* __restrict__ gate,
    const float* __restrict__ gamma, const float* __restrict__ beta,
    float* __restrict__ og)
{
    const int blk = blockIdx.x;
    const int c  = blk & (NC - 1);
    const int bh = blk >> 7;
    const int h = bh & 15, b = bh >> 4;
    const int d = threadIdx.x;

    __shared__ float sQ[CHUNK][65];
    __shared__ float sKf[DIN + CHUNK][65];
    __shared__ float sS[CHUNK][21];
    __shared__ float sO[CHUNK][65];
    __shared__ float sMu[CHUNK], sRs[CHUNK];

    float vf[DIN + CHUNK];

    const size_t wofs = (size_t)blk * (DIN * 64) + d;
#pragma unroll
    for (int n = 0; n < DIN; ++n) {
        sKf[n][d] = wst_in [wofs + n * 64];
        vf[n]     = wst_out[wofs + n * 64];
    }
    const size_t base = ((size_t)b * SEQ + c * CHUNK) * DIM + h * 64 + d;
#pragma unroll
    for (int i = 0; i < CHUNK; ++i) {
        sQ[i][d]        = qconv[base + (size_t)i * DIM];
        sKf[DIN + i][d] = kconv[base + (size_t)i * DIM];
        vf[DIN + i]     = vconv[base + (size_t)i * DIM];
    }
    __syncthreads();

#pragma unroll
    for (int r = 0; r < 5; ++r) {
        const int p = d + 64 * r;
        const int t = p / 20, j = p % 20;
        float dot = 0.f;
#pragma unroll
        for (int dd = 0; dd < 64; ++dd) dot += sQ[t][dd] * sKf[j][dd];
        float s = dot * SCALE;
        if (j >= DIN && (j - DIN) > t) s = -3.0e38f;
        sS[t][j] = s;
    }
    __syncthreads();

    if (d < CHUNK) {
        float m = -3.0e38f;
#pragma unroll
        for (int j = 0; j < DIN + CHUNK; ++j) m = fmaxf(m, sS[d][j]);
        float e[DIN + CHUNK];
        float sum = 0.f;
#pragma unroll
        for (int j = 0; j < DIN + CHUNK; ++j) { e[j] = expf(sS[d][j] - m); sum += e[j]; }
        const float inv = 1.f / sum;
#pragma unroll
        for (int j = 0; j < DIN + CHUNK; ++j) sS[d][j] = e[j] * inv;
    }
    __syncthreads();

#pragma unroll
    for (int t = 0; t < CHUNK; ++t) {
        float o = 0.f;
#pragma unroll
        for (int j = 0; j < DIN + CHUNK; ++j) o += sS[t][j] * vf[j];
        sO[t][d] = o;
    }
    __syncthreads();

    if (d < CHUNK) {
        float su = 0.f, sq = 0.f;
#pragma unroll
        for (int dd = 0; dd < 64; ++dd) { float x = sO[d][dd]; su += x; sq += x * x; }
        float mu = su * (1.f / 64.f);
        float var = sq * (1.f / 64.f) - mu * mu;
        sMu[d] = mu;
        sRs[d] = rsqrtf(var + LN_EPS);
    }
    __syncthreads();

    const float gm = gamma[d], bt = beta[d];
#pragma unroll
    for (int t = 0; t < CHUNK; ++t) {
        float val = (sO[t][d] - sMu[t]) * sRs[t] * gm + bt;
        float gval = gate[base + (size_t)t * DIM];
        og[base + (size_t)t * DIM] = val * gval;
    }
}

// ---------------------------------------------------------------------------
// Workspace layout (high-water ~236.4 MB; proven bound 242.2 MB).
// spar aliases Bbuf (disjoint lifetimes, all dispatches stream-serialized).
// ---------------------------------------------------------------------------
extern "C" void kernel_launch(void* const* d_in, const int* in_sizes, int n_in,
                              void* d_out, int out_size, void* d_ws, size_t ws_size,
                              hipStream_t stream)
{
    const float* hid   = (const float*)d_in[0];
    const float* Wq    = (const float*)d_in[1];
    const float* Wk    = (const float*)d_in[2];
    const float* Wv    = (const float*)d_in[3];
    const float* Wlr   = (const float*)d_in[4];
    const float* Wo    = (const float*)d_in[5];
    const float* Wg    = (const float*)d_in[6];
    const float* cq    = (const float*)d_in[7];
    const float* ck    = (const float*)d_in[8];
    const float* cv    = (const float*)d_in[9];
    const float* wini  = (const float*)d_in[10];
    const float* wouti = (const float*)d_in[11];
    const float* lng   = (const float*)d_in[12];
    const float* lnb   = (const float*)d_in[13];
    float* out = (float*)d_out;

    float* ws = (float*)d_ws;
    const size_t DSZ = (size_t)TOK * DIM;
    float* qraw  = ws;
    float* kraw  = qraw + DSZ;
    float* vraw  = kraw + DSZ;
    float* gatb  = vraw + DSZ;
    float* lrpre = gatb + DSZ;                         // TOK*32
    float* lrm   = lrpre + (size_t)TOK * 32;           // 16384
    float* wsti  = lrm   + BATCH * NC * NH * 2;
    float* wsto  = wsti  + (size_t)BATCH * NH * NC * DIN * 64;
    unsigned short* Abuf = (unsigned short*)(wsto + (size_t)BATCH * NH * NC * DIN * 64);
    unsigned short* Bbuf = Abuf + (size_t)TOK * K3;    // [4096][K3]
    float* spar = (float*)Bbuf;        // aliases Bbuf (disjoint lifetimes)

    // buffer ping-pong: qv = spar, kv = qraw, vv = kraw (after convs)
    float* qv = spar;
    float* kv = qraw;
    float* vv = kraw;

    const dim3 blk256(256);
    const dim3 fused_grid(16, 32);                     // 256^2 tiles: N=4096, M=8192
    const dim3 out_grid(8, 64);                        // final Wo GEMM (128^2)
    const dim3 gemm_grid_lr(1, TOK / GBM);
    const int conv_blocks = (TOK * 256 + 255) / 256;

    // splits: hidden -> Abuf; 4 weights -> Bbuf row blocks
    split_bf16_kernel<<<TOK, blk256, 0, stream>>>(hid, Abuf, TOK, 0);
    split_bf16_kernel<<<1024, blk256, 0, stream>>>(Wq, Bbuf,                       1024, 1);
    split_bf16_kernel<<<1024, blk256, 0, stream>>>(Wk, Bbuf + (size_t)1024 * K3,   1024, 1);
    split_bf16_kernel<<<1024, blk256, 0, stream>>>(Wv, Bbuf + (size_t)2048 * K3,   1024, 1);
    split_bf16_kernel<<<1024, blk256, 0, stream>>>(Wg, Bbuf + (size_t)3072 * K3,   1024, 1);

    // fused q/k/v/gate projection (256^2 pipelined)
    gemm_mfma_qkvg<<<fused_grid, 512, 0, stream>>>(Abuf, Bbuf, qraw, kraw, vraw, gatb);

    // convs (ordering matters; conv-q's write to spar retires Bbuf)
    conv_res_kernel<<<conv_blocks, blk256, 0, stream>>>(qraw, cq, spar);  // qv
    conv_res_kernel<<<conv_blocks, blk256, 0, stream>>>(kraw, ck, qraw);  // kv
    conv_res_kernel<<<conv_blocks, blk256, 0, stream>>>(vraw, cv, kraw);  // vv

    // lr path (f32, N=32)
    gemm_nt_f32<<<gemm_grid_lr, blk256, 0, stream>>>(hid, Wlr, lrpre, TOK, 32, DIM);
    lrmean_kernel<<<(BATCH * NC * NH * 2 + 255) / 256, blk256, 0, stream>>>(lrpre, lrm);

    // fast-weight state scan (2-wave blocks) + attention
    state_scan_kernel<<<BATCH * NH, 128, 0, stream>>>(kv, vv, lrm, wini, wouti, wsti, wsto);
    attn_kernel<<<BATCH * NH * NC, 64, 0, stream>>>(qv, kv, vv, wsti, wsto,
                                                    gatb, lng, lnb, qv);

    // output projection: (o*gate) @ Wo^T
    split_bf16_kernel<<<TOK, blk256, 0, stream>>>(qv, Abuf, TOK, 0);
    split_bf16_kernel<<<1024, blk256, 0, stream>>>(Wo, Bbuf, 1024, 1);
    gemm_mfma_bt<<<out_grid, blk256, 0, stream>>>(Abuf, Bbuf, out, TOK, DIM);
}

// Round 10
// 795.822 us; speedup vs baseline: 1.3573x; 1.1134x over previous
//
#include <hip/hip_runtime.h>
#include <hip/hip_bf16.h>
#include <math.h>

// Problem constants
#define BATCH 4
#define SEQ   2048
#define DIM   1024
#define NH    16
#define DQK   64
#define DV    64
#define DIN   4
#define CHUNK 16
#define NC    128          // SEQ / CHUNK
#define KS    4
#define TOK   (BATCH*SEQ)  // 8192
#define SCALE 0.125f       // 1/sqrt(64)
#define BASE_LR 1e-3f
#define LN_EPS 1e-5f
#define K3    3072         // split-GEMM inner dim: [hi|hi|lo] x [hi|lo|hi]

typedef float f32x4 __attribute__((ext_vector_type(4)));
typedef short s16x8 __attribute__((ext_vector_type(8)));

// ---------------------------------------------------------------------------
// bf16 helpers (bit-level, no header-type dependence)
// ---------------------------------------------------------------------------
__device__ __forceinline__ unsigned short f2bf(float f) {
    unsigned u = __float_as_uint(f);
    u += 0x7fffu + ((u >> 16) & 1u);           // round-to-nearest-even
    return (unsigned short)(u >> 16);
}
__device__ __forceinline__ float bf2f(unsigned short h) {
    return __uint_as_float(((unsigned)h) << 16);
}

__device__ __forceinline__ void gload_lds16(const void* g, void* l) {
    __builtin_amdgcn_global_load_lds(
        (const __attribute__((address_space(1))) void*)g,
        (__attribute__((address_space(3))) void*)l, 16, 0, 0);
}

// ---------------------------------------------------------------------------
// Split f32 -> bf16 hi/lo, concatenated along K.
// wmode 0 (A side): cols [0,1024)=hi [1024,2048)=hi [2048,3072)=lo
// wmode 1 (B side): cols [0,1024)=hi [1024,2048)=lo [2048,3072)=hi
// ---------------------------------------------------------------------------
__global__ __launch_bounds__(256) void split_bf16_kernel(
    const float* __restrict__ X, unsigned short* __restrict__ Y,
    int rows, int wmode)
{
    const int idx = blockIdx.x * 256 + threadIdx.x;
    if (idx >= rows * (DIM / 4)) return;
    const int r  = idx >> 8;          // DIM/4 = 256 groups per row
    const int c4 = (idx & 255) << 2;

    float4 x = *(const float4*)(X + (size_t)r * DIM + c4);
    ushort4 hv, lv;
    hv.x = f2bf(x.x); lv.x = f2bf(x.x - bf2f(hv.x));
    hv.y = f2bf(x.y); lv.y = f2bf(x.y - bf2f(hv.y));
    hv.z = f2bf(x.z); lv.z = f2bf(x.z - bf2f(hv.z));
    hv.w = f2bf(x.w); lv.w = f2bf(x.w - bf2f(hv.w));

    const size_t rb = (size_t)r * K3;
    *(ushort4*)(Y + rb + c4)        = hv;
    *(ushort4*)(Y + rb + 1024 + c4) = wmode ? lv : hv;
    *(ushort4*)(Y + rb + 2048 + c4) = wmode ? hv : lv;
}

// ---------------------------------------------------------------------------
// Fused MFMA GEMM (8-phase m201-style schedule).
// 256x256 tile, BK=64, 8 waves (2Mx4N), 512 thr, LDS 128 KiB (1 block/CU).
// Per K-tile: 4 phases {issue stage gloads; 8 ds_read_b128; barrier;
// lgkmcnt(0); setprio(1); 16 MFMA; setprio(0); barrier}.
// Tile t+1 staged during phases 1-4 (buf1 free), t+2 during phases 5-8
// (buf0 free). vmcnt(0) twice per 2 K-tiles; tail loads have ~1.5-phase
// issue lead. All barriers block-uniform. Per-acc K-order unchanged ->
// output BIT-IDENTICAL to rounds 7/8.
// ---------------------------------------------------------------------------
__global__ __launch_bounds__(512, 1) void gemm_mfma_qkvg(
    const unsigned short* __restrict__ A, const unsigned short* __restrict__ B,
    float* __restrict__ Cq, float* __restrict__ Ck,
    float* __restrict__ Cv, float* __restrict__ Cg)
{
    __shared__ __align__(16) unsigned short sA[2][256 * 64];
    __shared__ __align__(16) unsigned short sB[2][256 * 64];

    const int tid  = threadIdx.x;
    const int lane = tid & 63;
    const int wid  = tid >> 6;

    // XCD swizzle: grid (16,32) -> nwg=512, %8==0 -> bijective
    const int nbx = gridDim.x;                  // 16
    const int nwg = nbx * gridDim.y;            // 512
    int flat = blockIdx.x + blockIdx.y * nbx;
    const int per = nwg >> 3;
    flat = (flat & 7) * per + (flat >> 3);
    const int m0 = (flat / nbx) * 256;
    const int n0 = (flat % nbx) * 256;

    const int wm = (wid >> 2) * 128;    // 2 M-rows of waves
    const int wn = (wid & 3) * 64;      // 4 N-cols of waves

    f32x4 acc[8][4] = {};

    const int lrow = lane & 15;
    const int g    = lane >> 4;

// single 16B stage load: matrix M in {A->sA, B->sB}, slot index i (0..3)
#define SL_A(db, ktile, i)                                                     \
    do {                                                                       \
        const int f_ = tid + (i) * 512;                                        \
        const int r_ = f_ >> 3;                                                \
        const int c_ = (f_ & 7) ^ (r_ & 7);                                    \
        gload_lds16(A + (size_t)(m0 + r_) * K3 + (ktile) * 64 + c_ * 8,        \
                    (char*)sA[db] + (wid * 64 + (i) * 512) * 16);              \
    } while (0)
#define SL_B(db, ktile, i)                                                     \
    do {                                                                       \
        const int f_ = tid + (i) * 512;                                        \
        const int r_ = f_ >> 3;                                                \
        const int c_ = (f_ & 7) ^ (r_ & 7);                                    \
        gload_lds16(B + (size_t)(n0 + r_) * K3 + (ktile) * 64 + c_ * 8,        \
                    (char*)sB[db] + (wid * 64 + (i) * 512) * 16);              \
    } while (0)

// one phase: stage hook, 8 ds_reads, barrier, lgkmcnt, 16 MFMA, barrier
#define PHASE(db, ks, mh, SCODE)                                               \
    do {                                                                       \
        SCODE;                                                                 \
        const char* pA_ = (const char*)sA[db];                                 \
        const char* pB_ = (const char*)sB[db];                                 \
        s16x8 af[4], bfr[4];                                                   \
        _Pragma("unroll")                                                      \
        for (int j = 0; j < 4; ++j) {                                          \
            const int r_  = wm + ((mh) * 4 + j) * 16 + lrow;                   \
            const int cs_ = ((ks) * 4 + g) ^ (r_ & 7);                         \
            af[j] = *(const s16x8*)(pA_ + r_ * 128 + cs_ * 16);                \
        }                                                                      \
        _Pragma("unroll")                                                      \
        for (int ni = 0; ni < 4; ++ni) {                                       \
            const int r_  = wn + ni * 16 + lrow;                               \
            const int cs_ = ((ks) * 4 + g) ^ (r_ & 7);                         \
            bfr[ni] = *(const s16x8*)(pB_ + r_ * 128 + cs_ * 16);              \
        }                                                                      \
        asm volatile("" ::: "memory");                                         \
        __builtin_amdgcn_s_barrier();                                          \
        asm volatile("s_waitcnt lgkmcnt(0)" ::: "memory");                     \
        __builtin_amdgcn_s_setprio(1);                                         \
        _Pragma("unroll")                                                      \
        for (int j = 0; j < 4; ++j)                                            \
            _Pragma("unroll")                                                  \
            for (int ni = 0; ni < 4; ++ni)                                     \
                acc[(mh) * 4 + j][ni] = __builtin_amdgcn_mfma_f32_16x16x32_bf16( \
                    af[j], bfr[ni], acc[(mh) * 4 + j][ni], 0, 0, 0);           \
        __builtin_amdgcn_s_setprio(0);                                         \
        asm volatile("" ::: "memory");                                         \
        __builtin_amdgcn_s_barrier();                                          \
        asm volatile("" ::: "memory");                                         \
    } while (0)

    // prologue: stage tile 0 -> buf0 (8 loads in flight)
    SL_A(0, 0, 0); SL_A(0, 0, 1); SL_A(0, 0, 2); SL_A(0, 0, 3);
    SL_B(0, 0, 0); SL_B(0, 0, 1); SL_B(0, 0, 2); SL_B(0, 0, 3);

    const int NT = K3 / 64;             // 48
    for (int i = 0; i < NT / 2; ++i) {
        const int t1 = 2 * i + 1;       // odd tile -> buf1
        const int t2 = 2 * i + 2;       // next even tile -> buf0
        const bool more = (t2 < NT);

        // buf0 (tile 2i) loaded block-wide
        asm volatile("s_waitcnt vmcnt(0)" ::: "memory");
        asm volatile("" ::: "memory");
        __builtin_amdgcn_s_barrier();

        // phases 1-4: compute buf0; stage tile t1 -> buf1 (3,3,2,0)
        PHASE(0, 0, 0, { SL_A(1, t1, 0); SL_A(1, t1, 1); SL_A(1, t1, 2); });
        PHASE(0, 0, 1, { SL_A(1, t1, 3); SL_B(1, t1, 0); SL_B(1, t1, 1); });
        PHASE(0, 1, 0, { SL_B(1, t1, 2); SL_B(1, t1, 3); });
        PHASE(0, 1, 1, { });

        // buf1 (tile t1) loaded block-wide
        asm volatile("s_waitcnt vmcnt(0)" ::: "memory");
        asm volatile("" ::: "memory");
        __builtin_amdgcn_s_barrier();

        // phases 5-8: compute buf1; stage tile t2 -> buf0 (3,3,2,0)
        PHASE(1, 0, 0, { if (more) { SL_A(0, t2, 0); SL_A(0, t2, 1); SL_A(0, t2, 2); } });
        PHASE(1, 0, 1, { if (more) { SL_A(0, t2, 3); SL_B(0, t2, 0); SL_B(0, t2, 1); } });
        PHASE(1, 1, 0, { if (more) { SL_B(0, t2, 2); SL_B(0, t2, 3); } });
        PHASE(1, 1, 1, { });
    }
#undef PHASE
#undef SL_A
#undef SL_B

    // epilogue: wave-uniform output select (256-tile never straddles 1024)
    const int nblk = n0 >> 10;
    float* __restrict__ Co = (nblk == 0) ? Cq : (nblk == 1) ? Ck
                           : (nblk == 2) ? Cv : Cg;
    const int nc0 = (n0 & 1023) + wn;
    const int lcol = lane & 15;
    const int lq   = lane >> 4;
#pragma unroll
    for (int mi = 0; mi < 8; ++mi)
#pragma unroll
        for (int ni = 0; ni < 4; ++ni)
#pragma unroll
            for (int r = 0; r < 4; ++r) {
                const int m = m0 + wm + mi * 16 + lq * 4 + r;
                const int n = nc0 + ni * 16 + lcol;
                Co[(size_t)m * DIM + n] = acc[mi][ni][r];
            }
}

// ---------------------------------------------------------------------------
// MFMA GEMM (bf16, NT), single output: used for the final Wo projection.
// (unchanged 128^2 m97-structure - proven)
// ---------------------------------------------------------------------------
__global__ __launch_bounds__(256) void gemm_mfma_bt(
    const unsigned short* __restrict__ A, const unsigned short* __restrict__ B,
    float* __restrict__ C, int M, int N)
{
    __shared__ __align__(16) unsigned short sA[128 * 64];
    __shared__ __align__(16) unsigned short sB[128 * 64];

    const int tid  = threadIdx.x;
    const int lane = tid & 63;
    const int wav  = tid >> 6;

    const int nbx = gridDim.x;
    const int nwg = nbx * gridDim.y;
    int flat = blockIdx.x + blockIdx.y * nbx;
    const int per = nwg >> 3;
    flat = (flat & 7) * per + (flat >> 3);
    const int m0 = (flat / nbx) * 128;
    const int n0 = (flat % nbx) * 128;

    const int wm = (wav >> 1) * 64;
    const int wn = (wav & 1) * 64;

    f32x4 acc[4][4] = {};

    const int fbase = wav * 64 + lane;
    const int lrow  = lane & 15;
    const int g     = lane >> 4;

    for (int kt = 0; kt < K3; kt += 64) {
        __syncthreads();
#pragma unroll
        for (int i = 0; i < 4; ++i) {
            const int f  = fbase + i * 256;
            const int r  = f >> 3;
            const int c  = (f & 7) ^ (r & 7);
            const size_t go = (size_t)r * K3 + kt + c * 8;
            char* lb = (char*)sA + (wav * 64 + i * 256) * 16;
            gload_lds16(A + (size_t)m0 * K3 + go, lb);
        }
#pragma unroll
        for (int i = 0; i < 4; ++i) {
            const int f  = fbase + i * 256;
            const int r  = f >> 3;
            const int c  = (f & 7) ^ (r & 7);
            const size_t go = (size_t)r * K3 + kt + c * 8;
            char* lb = (char*)sB + (wav * 64 + i * 256) * 16;
            gload_lds16(B + (size_t)n0 * K3 + go, lb);
        }
        __syncthreads();

#pragma unroll
        for (int ks = 0; ks < 2; ++ks) {
            const int cbase = ks * 4 + g;
            s16x8 af[4], bfr[4];
#pragma unroll
            for (int mi = 0; mi < 4; ++mi) {
                const int r  = wm + mi * 16 + lrow;
                const int cs = cbase ^ (r & 7);
                af[mi] = *(const s16x8*)((const char*)sA + r * 128 + cs * 16);
            }
#pragma unroll
            for (int ni = 0; ni < 4; ++ni) {
                const int r  = wn + ni * 16 + lrow;
                const int cs = cbase ^ (r & 7);
                bfr[ni] = *(const s16x8*)((const char*)sB + r * 128 + cs * 16);
            }
#pragma unroll
            for (int mi = 0; mi < 4; ++mi)
#pragma unroll
                for (int ni = 0; ni < 4; ++ni)
                    acc[mi][ni] = __builtin_amdgcn_mfma_f32_16x16x32_bf16(
                        af[mi], bfr[ni], acc[mi][ni], 0, 0, 0);
        }
    }

    const int lcol = lane & 15;
    const int lq   = lane >> 4;
#pragma unroll
    for (int mi = 0; mi < 4; ++mi)
#pragma unroll
        for (int ni = 0; ni < 4; ++ni)
#pragma unroll
            for (int r = 0; r < 4; ++r) {
                const int m = m0 + wm + mi * 16 + lq * 4 + r;
                const int n = n0 + wn + ni * 16 + lcol;
                C[(size_t)m * N + n] = acc[mi][ni][r];
            }
}

// ---------------------------------------------------------------------------
// lr projection: MFMA with 4-way K-split. Grid (4 kslices, 64).
// A = Abuf (hidden split, [TOK][K3]); Bl = WlrB ([128][K3], rows 0-31 real,
// rows 32-127 stale-poison garbage -> finite bf16, their columns never
// stored). Each block: 128 M-rows x 128 N-cols over K3/4=768 (12 K-tiles).
// Epilogue stores only n<32 (waves with wn==0, ni<2) to its K-partial:
// lrp[kb][m][n]. lrmean sums the 4 partials in K-order.
// ---------------------------------------------------------------------------
__global__ __launch_bounds__(256) void gemm_mfma_lr(
    const unsigned short* __restrict__ A, const unsigned short* __restrict__ Bl,
    float* __restrict__ lrp)
{
    __shared__ __align__(16) unsigned short sA[128 * 64];
    __shared__ __align__(16) unsigned short sB[128 * 64];

    const int tid  = threadIdx.x;
    const int lane = tid & 63;
    const int wav  = tid >> 6;
    const int kb   = blockIdx.x;        // 0..3 K-slice
    const int m0   = blockIdx.y * 128;

    const int wm = (wav >> 1) * 64;
    const int wn = (wav & 1) * 64;

    f32x4 acc[4][4] = {};

    const int fbase = wav * 64 + lane;
    const int lrow  = lane & 15;
    const int g     = lane >> 4;

    const int k0 = kb * (K3 / 4);       // 768-wide slice
    for (int kt = k0; kt < k0 + K3 / 4; kt += 64) {
        __syncthreads();
#pragma unroll
        for (int i = 0; i < 4; ++i) {
            const int f  = fbase + i * 256;
            const int r  = f >> 3;
            const int c  = (f & 7) ^ (r & 7);
            gload_lds16(A + (size_t)(m0 + r) * K3 + kt + c * 8,
                        (char*)sA + (wav * 64 + i * 256) * 16);
        }
#pragma unroll
        for (int i = 0; i < 4; ++i) {
            const int f  = fbase + i * 256;
            const int r  = f >> 3;
            const int c  = (f & 7) ^ (r & 7);
            gload_lds16(Bl + (size_t)r * K3 + kt + c * 8,
                        (char*)sB + (wav * 64 + i * 256) * 16);
        }
        __syncthreads();

#pragma unroll
        for (int ks = 0; ks < 2; ++ks) {
            const int cbase = ks * 4 + g;
            s16x8 af[4], bfr[4];
#pragma unroll
            for (int mi = 0; mi < 4; ++mi) {
                const int r  = wm + mi * 16 + lrow;
                const int cs = cbase ^ (r & 7);
                af[mi] = *(const s16x8*)((const char*)sA + r * 128 + cs * 16);
            }
#pragma unroll
            for (int ni = 0; ni < 4; ++ni) {
                const int r  = wn + ni * 16 + lrow;
                const int cs = cbase ^ (r & 7);
                bfr[ni] = *(const s16x8*)((const char*)sB + r * 128 + cs * 16);
            }
#pragma unroll
            for (int mi = 0; mi < 4; ++mi)
#pragma unroll
                for (int ni = 0; ni < 4; ++ni)
                    acc[mi][ni] = __builtin_amdgcn_mfma_f32_16x16x32_bf16(
                        af[mi], bfr[ni], acc[mi][ni], 0, 0, 0);
        }
    }

    if (wn != 0) return;                // only cols 0-63 waves hold n<32
    const int lcol = lane & 15;
    const int lq   = lane >> 4;
    float* dst = lrp + (size_t)kb * TOK * 32;
#pragma unroll
    for (int mi = 0; mi < 4; ++mi)
#pragma unroll
        for (int ni = 0; ni < 2; ++ni)  // n = ni*16+lcol in [0,32)
#pragma unroll
            for (int r = 0; r < 4; ++r) {
                const int m = m0 + wm + mi * 16 + lq * 4 + r;
                const int n = ni * 16 + lcol;
                dst[(size_t)m * 32 + n] = acc[mi][ni][r];
            }
}

// ---------------------------------------------------------------------------
// Causal depthwise conv (KS=4) + identity residual.
// ---------------------------------------------------------------------------
__global__ __launch_bounds__(256) void conv_res_kernel(
    const float* __restrict__ x, const float* __restrict__ w,
    float* __restrict__ y)
{
    const int tid = blockIdx.x * blockDim.x + threadIdx.x;
    if (tid >= TOK * 256) return;
    const int c4  = (tid & 255) << 2;
    const int row = tid >> 8;
    const int t   = row & (SEQ - 1);

    const float* xp = x + (size_t)row * DIM + c4;
    float4 acc = *(const float4*)xp;      // residual
    float4 w0 = *(const float4*)(w + (c4 + 0) * 4);
    float4 w1 = *(const float4*)(w + (c4 + 1) * 4);
    float4 w2 = *(const float4*)(w + (c4 + 2) * 4);
    float4 w3 = *(const float4*)(w + (c4 + 3) * 4);

#pragma unroll
    for (int j = 0; j < 4; ++j) {
        const int tt = t - 3 + j;
        if (tt >= 0) {
            float4 xv = *(const float4*)(xp + (j - 3) * DIM);
            acc.x += xv.x * ((&w0.x)[j]);
            acc.y += xv.y * ((&w1.x)[j]);
            acc.z += xv.z * ((&w2.x)[j]);
            acc.w += xv.w * ((&w3.x)[j]);
        }
    }
    *(float4*)(y + (size_t)row * DIM + c4) = acc;
}

// ---------------------------------------------------------------------------
// lr chunk means (sums 4 K-partials, then softplus, then mean).
// ---------------------------------------------------------------------------
__global__ __launch_bounds__(256) void lrmean_kernel(
    const float* __restrict__ lrp, float* __restrict__ lrm)
{
    const int idx = blockIdx.x * blockDim.x + threadIdx.x;
    if (idx >= BATCH * NC * NH * 2) return;
    const int j = idx & 1;
    const int h = (idx >> 1) & 15;
    const int c = (idx >> 5) & 127;
    const int b = idx >> 12;

    const size_t T32 = (size_t)TOK * 32;
    float s = 0.f;
#pragma unroll
    for (int i = 0; i < CHUNK; ++i) {
        const size_t e = ((size_t)b * SEQ + c * CHUNK + i) * 32 + h * 2 + j;
        float x = ((lrp[e] + lrp[T32 + e]) + (lrp[2 * T32 + e] + lrp[3 * T32 + e]))
                  + BASE_LR;
        s += fmaxf(x, 0.f) + log1pf(expf(-fabsf(x)));   // stable softplus
    }
    lrm[idx] = s * (1.f / CHUNK);
}

// ---------------------------------------------------------------------------
// Pass 1: 2-wave role-split scan (unchanged from round 7).
// ---------------------------------------------------------------------------
__global__ __launch_bounds__(128) void state_scan_kernel(
    const float* __restrict__ kconv, const float* __restrict__ vconv,
    const float* __restrict__ lrm,
    const float* __restrict__ win_init, const float* __restrict__ wout_init,
    float* __restrict__ wst_in, float* __restrict__ wst_out)
{
    const int bh  = blockIdx.x;
    const int b   = bh >> 4, h = bh & 15;
    const int tid = threadIdx.x;
    const int wv  = tid >> 6;          // 0 = k/W_in wave, 1 = v/W_out wave
    const int d   = tid & 63;

    __shared__ __align__(16) float sW[DIN][68];
    __shared__ __align__(16) float sK[CHUNK][68];
    __shared__ __align__(16) float sP1[2][DIN][16];
    __shared__ __align__(16) float sP2[2][DIN][16];
    __shared__ float sLR[NC * 2];

    const float* __restrict__ xin  = wv ? vconv     : kconv;
    const float* __restrict__ wini = wv ? wout_init : win_init;
    float*       __restrict__ wst  = wv ? wst_out   : wst_in;

    float W[DIN];
#pragma unroll
    for (int n = 0; n < DIN; ++n) W[n] = wini[(n * NH + h) * 64 + d];

    sLR[tid * 2 + 0] = lrm[(((size_t)b * NC + tid) * NH + h) * 2 + 0];
    sLR[tid * 2 + 1] = lrm[(((size_t)b * NC + tid) * NH + h) * 2 + 1];

    const int gn = d >> 4;
    const int gc = d & 15;

    float xa[CHUNK], xb[CHUNK];
    const size_t base00 = (size_t)b * SEQ * DIM + h * 64 + d;
#pragma unroll
    for (int i = 0; i < CHUNK; ++i) xa[i] = xin[base00 + (size_t)i * DIM];
    asm volatile("s_waitcnt lgkmcnt(0)" ::: "memory");

#define SCAN_STEP(c, XA, XB)                                                   \
    {                                                                          \
        const int pb = (c) & 1;                                                \
        if ((c) + 1 < NC) {                                                    \
            const size_t basen = base00 + (size_t)(((c) + 1) * CHUNK) * DIM;   \
            _Pragma("unroll")                                                  \
            for (int i = 0; i < CHUNK; ++i)                                    \
                XB[i] = xin[basen + (size_t)i * DIM];                          \
        }                                                                      \
        const size_t wofs = (((size_t)bh * NC + (c)) * DIN) * 64 + d;          \
        _Pragma("unroll")                                                      \
        for (int n = 0; n < DIN; ++n) wst[wofs + n * 64] = W[n];               \
        if (wv == 0) {                                                         \
            _Pragma("unroll")                                                  \
            for (int i = 0; i < CHUNK; ++i) sK[i][d] = XA[i];                  \
            _Pragma("unroll")                                                  \
            for (int n = 0; n < DIN; ++n) sW[n][d] = W[n];                     \
            asm volatile("s_waitcnt lgkmcnt(0)" ::: "memory");                 \
            float p0 = 0.f, p1 = 0.f, p2 = 0.f, p3 = 0.f;                      \
            _Pragma("unroll")                                                  \
            for (int q = 0; q < 4; ++q) {                                      \
                const int o = q * 16;                                          \
                float4 w0 = *(const float4*)&sW[gn][o + 0];                    \
                float4 k0 = *(const float4*)&sK[gc][o + 0];                    \
                float4 w1 = *(const float4*)&sW[gn][o + 4];                    \
                float4 k1 = *(const float4*)&sK[gc][o + 4];                    \
                float4 w2 = *(const float4*)&sW[gn][o + 8];                    \
                float4 k2 = *(const float4*)&sK[gc][o + 8];                    \
                float4 w3 = *(const float4*)&sW[gn][o + 12];                   \
                float4 k3 = *(const float4*)&sK[gc][o + 12];                   \
                p0 += w0.x*k0.x; p0 += w0.y*k0.y; p0 += w0.z*k0.z; p0 += w0.w*k0.w; \
                p1 += w1.x*k1.x; p1 += w1.y*k1.y; p1 += w1.z*k1.z; p1 += w1.w*k1.w; \
                p2 += w2.x*k2.x; p2 += w2.y*k2.y; p2 += w2.z*k2.z; p2 += w2.w*k2.w; \
                p3 += w3.x*k3.x; p3 += w3.y*k3.y; p3 += w3.z*k3.z; p3 += w3.w*k3.w; \
            }                                                                  \
            const float g1 = ((p0 + p1) + (p2 + p3)) * SCALE;                  \
            float m = g1;                                                      \
            _Pragma("unroll")                                                  \
            for (int mk = 8; mk >= 1; mk >>= 1)                                \
                m = fmaxf(m, __shfl_xor(m, mk, 16));                           \
            const float e1 = expf(g1 - m);                                     \
            const float rr = sqrtf(e1);   /* = exp(g1/2 - m/2) */              \
            float s1 = e1, s2 = rr;                                            \
            _Pragma("unroll")                                                  \
            for (int mk = 8; mk >= 1; mk >>= 1) {                              \
                s1 += __shfl_xor(s1, mk, 16);                                  \
                s2 += __shfl_xor(s2, mk, 16);                                  \
            }                                                                  \
            sP1[pb][gn][gc] = e1 / s1;                                         \
            sP2[pb][gn][gc] = rr / s2;                                         \
            asm volatile("s_waitcnt lgkmcnt(0)" ::: "memory");                 \
        }                                                                      \
        __builtin_amdgcn_s_barrier();                                          \
        const float lr = sLR[(c) * 2 + wv];                                    \
        const float (*P)[16] = wv ? sP1[pb] : sP2[pb];                         \
        _Pragma("unroll")                                                      \
        for (int n = 0; n < DIN; ++n) {                                        \
            float4 q0 = *(const float4*)&P[n][0];                              \
            float4 q1 = *(const float4*)&P[n][4];                              \
            float4 q2 = *(const float4*)&P[n][8];                              \
            float4 q3 = *(const float4*)&P[n][12];                             \
            float t0 = q0.x*XA[0];  t0 += q0.y*XA[1];                          \
            t0 += q0.z*XA[2];       t0 += q0.w*XA[3];                          \
            float t1 = q1.x*XA[4];  t1 += q1.y*XA[5];                          \
            t1 += q1.z*XA[6];       t1 += q1.w*XA[7];                          \
            float t2 = q2.x*XA[8];  t2 += q2.y*XA[9];                          \
            t2 += q2.z*XA[10];      t2 += q2.w*XA[11];                         \
            float t3 = q3.x*XA[12]; t3 += q3.y*XA[13];                         \
            t3 += q3.z*XA[14];      t3 += q3.w*XA[15];                         \
            W[n] += lr * ((t0 + t1) + (t2 + t3));                              \
        }                                                                      \
    }

    for (int c = 0; c < NC; c += 2) {
        SCAN_STEP(c,     xa, xb);
        SCAN_STEP(c + 1, xb, xa);
    }
#undef SCAN_STEP
}

// ---------------------------------------------------------------------------
// Pass 2: per-(b,h,chunk) attention + LayerNorm + gate (unchanged).
// ---------------------------------------------------------------------------
__global__ __launch_bounds__(64) void attn_kernel(
    const float* __restrict__ qconv, const float* __restrict__ kconv,
    const float* __restrict__ vconv,
    const float* __restrict__ wst_in, const float* __restrict__ wst_out,
    const float* __restrict__ gate,
    const float* __restrict__ gamma, const float* __restrict__ beta,
    float* __restrict__ og)
{
    const int blk = blockIdx.x;
    const int c  = blk & (NC - 1);
    const int bh = blk >> 7;
    const int h = bh & 15, b = bh >> 4;
    const int d = threadIdx.x;

    __shared__ float sQ[CHUNK][65];
    __shared__ float sKf[DIN + CHUNK][65];
    __shared__ float sS[CHUNK][21];
    __shared__ float sO[CHUNK][65];
    __shared__ float sMu[CHUNK], sRs[CHUNK];

    float vf[DIN + CHUNK];

    const size_t wofs = (size_t)blk * (DIN * 64) + d;
#pragma unroll
    for (int n = 0; n < DIN; ++n) {
        sKf[n][d] = wst_in [wofs + n * 64];
        vf[n]     = wst_out[wofs + n * 64];
    }
    const size_t base = ((size_t)b * SEQ + c * CHUNK) * DIM + h * 64 + d;
#pragma unroll
    for (int i = 0; i < CHUNK; ++i) {
        sQ[i][d]        = qconv[base + (size_t)i * DIM];
        sKf[DIN + i][d] = kconv[base + (size_t)i * DIM];
        vf[DIN + i]     = vconv[base + (size_t)i * DIM];
    }
    __syncthreads();

#pragma unroll
    for (int r = 0; r < 5; ++r) {
        const int p = d + 64 * r;
        const int t = p / 20, j = p % 20;
        float dot = 0.f;
#pragma unroll
        for (int dd = 0; dd < 64; ++dd) dot += sQ[t][dd] * sKf[j][dd];
        float s = dot * SCALE;
        if (j >= DIN && (j - DIN) > t) s = -3.0e38f;
        sS[t][j] = s;
    }
    __syncthreads();

    if (d < CHUNK) {
        float m = -3.0e38f;
#pragma unroll
        for (int j = 0; j < DIN + CHUNK; ++j) m = fmaxf(m, sS[d][j]);
        float e[DIN + CHUNK];
        float sum = 0.f;
#pragma unroll
        for (int j = 0; j < DIN + CHUNK; ++j) { e[j] = expf(sS[d][j] - m); sum += e[j]; }
        const float inv = 1.f / sum;
#pragma unroll
        for (int j = 0; j < DIN + CHUNK; ++j) sS[d][j] = e[j] * inv;
    }
    __syncthreads();

#pragma unroll
    for (int t = 0; t < CHUNK; ++t) {
        float o = 0.f;
#pragma unroll
        for (int j = 0; j < DIN + CHUNK; ++j) o += sS[t][j] * vf[j];
        sO[t][d] = o;
    }
    __syncthreads();

    if (d < CHUNK) {
        float su = 0.f, sq = 0.f;
#pragma unroll
        for (int dd = 0; dd < 64; ++dd) { float x = sO[d][dd]; su += x; sq += x * x; }
        float mu = su * (1.f / 64.f);
        float var = sq * (1.f / 64.f) - mu * mu;
        sMu[d] = mu;
        sRs[d] = rsqrtf(var + LN_EPS);
    }
    __syncthreads();

    const float gm = gamma[d], bt = beta[d];
#pragma unroll
    for (int t = 0; t < CHUNK; ++t) {
        float val = (sO[t][d] - sMu[t]) * sRs[t] * gm + bt;
        float gval = gate[base + (size_t)t * DIM];
        og[base + (size_t)t * DIM] = val * gval;
    }
}

// ---------------------------------------------------------------------------
// Workspace layout (high-water ~239.9 MB; proven bound 242.2 MB):
//   qraw kraw vraw gatb (4 x 33.55 MB f32)
//   lrp (4 K-partials x TOK*32 f32 = 4.19 MB)
//   lrm (0.07)  wsti wsto (16.8 MB)
//   Abuf (50.33 MB bf16)
//   Bbuf (25.17 MB bf16) <- ALIASED by spar (33.55 MB f32, extends past Bbuf)
//   WlrB (0.79 MB bf16)  <- AFTER spar's extent (no overlap)
// spar/Bbuf lifetime disjointness: all dispatches stream-serialized.
// ---------------------------------------------------------------------------
extern "C" void kernel_launch(void* const* d_in, const int* in_sizes, int n_in,
                              void* d_out, int out_size, void* d_ws, size_t ws_size,
                              hipStream_t stream)
{
    const float* hid   = (const float*)d_in[0];
    const float* Wq    = (const float*)d_in[1];
    const float* Wk    = (const float*)d_in[2];
    const float* Wv    = (const float*)d_in[3];
    const float* Wlr   = (const float*)d_in[4];
    const float* Wo    = (const float*)d_in[5];
    const float* Wg    = (const float*)d_in[6];
    const float* cq    = (const float*)d_in[7];
    const float* ck    = (const float*)d_in[8];
    const float* cv    = (const float*)d_in[9];
    const float* wini  = (const float*)d_in[10];
    const float* wouti = (const float*)d_in[11];
    const float* lng   = (const float*)d_in[12];
    const float* lnb   = (const float*)d_in[13];
    float* out = (float*)d_out;

    float* ws = (float*)d_ws;
    const size_t DSZ = (size_t)TOK * DIM;
    float* qraw  = ws;
    float* kraw  = qraw + DSZ;
    float* vraw  = kraw + DSZ;
    float* gatb  = vraw + DSZ;
    float* lrp   = gatb + DSZ;                         // 4 x TOK*32
    float* lrm   = lrp  + (size_t)TOK * 128;           // 16384
    float* wsti  = lrm  + BATCH * NC * NH * 2;
    float* wsto  = wsti + (size_t)BATCH * NH * NC * DIN * 64;
    unsigned short* Abuf = (unsigned short*)(wsto + (size_t)BATCH * NH * NC * DIN * 64);
    unsigned short* Bbuf = Abuf + (size_t)TOK * K3;    // [4096][K3]
    float* spar = (float*)Bbuf;        // aliases Bbuf (disjoint lifetimes)
    unsigned short* WlrB = (unsigned short*)(spar + DSZ);  // [128][K3]

    // buffer ping-pong: qv = spar, kv = qraw, vv = kraw (after convs)
    float* qv = spar;
    float* kv = qraw;
    float* vv = kraw;

    const dim3 blk256(256);
    const dim3 fused_grid(16, 32);                     // 256^2 tiles
    const dim3 lr_grid(4, 64);                         // K-split lr GEMM
    const dim3 out_grid(8, 64);                        // final Wo GEMM (128^2)
    const int conv_blocks = (TOK * 256 + 255) / 256;

    // splits: hidden -> Abuf; 4 weights -> Bbuf row blocks; Wlr -> WlrB
    split_bf16_kernel<<<TOK, blk256, 0, stream>>>(hid, Abuf, TOK, 0);
    split_bf16_kernel<<<1024, blk256, 0, stream>>>(Wq, Bbuf,                       1024, 1);
    split_bf16_kernel<<<1024, blk256, 0, stream>>>(Wk, Bbuf + (size_t)1024 * K3,   1024, 1);
    split_bf16_kernel<<<1024, blk256, 0, stream>>>(Wv, Bbuf + (size_t)2048 * K3,   1024, 1);
    split_bf16_kernel<<<1024, blk256, 0, stream>>>(Wg, Bbuf + (size_t)3072 * K3,   1024, 1);
    split_bf16_kernel<<<32,   blk256, 0, stream>>>(Wlr, WlrB,                        32, 1);

    // fused q/k/v/gate projection (256^2, 8-phase)
    gemm_mfma_qkvg<<<fused_grid, 512, 0, stream>>>(Abuf, Bbuf, qraw, kraw, vraw, gatb);

    // lr projection (MFMA, 4-way K-split partials)
    gemm_mfma_lr<<<lr_grid, blk256, 0, stream>>>(Abuf, WlrB, lrp);

    // convs (ordering matters; conv-q's write to spar retires Bbuf)
    conv_res_kernel<<<conv_blocks, blk256, 0, stream>>>(qraw, cq, spar);  // qv
    conv_res_kernel<<<conv_blocks, blk256, 0, stream>>>(kraw, ck, qraw);  // kv
    conv_res_kernel<<<conv_blocks, blk256, 0, stream>>>(vraw, cv, kraw);  // vv

    // lr means (sums the 4 K-partials)
    lrmean_kernel<<<(BATCH * NC * NH * 2 + 255) / 256, blk256, 0, stream>>>(lrp, lrm);

    // fast-weight state scan (2-wave blocks) + attention
    state_scan_kernel<<<BATCH * NH, 128, 0, stream>>>(kv, vv, lrm, wini, wouti, wsti, wsto);
    attn_kernel<<<BATCH * NH * NC, 64, 0, stream>>>(qv, kv, vv, wsti, wsto,
                                                    gatb, lng, lnb, qv);

    // output projection: (o*gate) @ Wo^T
    split_bf16_kernel<<<TOK, blk256, 0, stream>>>(qv, Abuf, TOK, 0);
    split_bf16_kernel<<<1024, blk256, 0, stream>>>(Wo, Bbuf, 1024, 1);
    gemm_mfma_bt<<<out_grid, blk256, 0, stream>>>(Abuf, Bbuf, out, TOK, DIM);
}